// Round 1
// baseline (641.230 us; speedup 1.0000x reference)
//
#include <hip/hip_runtime.h>

#define N_NODES 50000
#define N_EDGES 800000
#define N_GRAPHS 512
#define C 128

// ---------- graph preprocessing ----------

__global__ void k_edge_deg(const int* __restrict__ dst, int* __restrict__ deg){
  int e = blockIdx.x*256 + threadIdx.x;
  if (e < N_EDGES) atomicAdd(&deg[dst[e]], 1);
}

__global__ void k_chunk_sum(const int* __restrict__ deg, int* __restrict__ chunkSum){
  __shared__ int s[256];
  int i = blockIdx.x*256 + threadIdx.x;
  int v = (i < N_NODES) ? deg[i] : 0;
  s[threadIdx.x] = v; __syncthreads();
  for (int off=128; off>0; off>>=1){
    if (threadIdx.x < off) s[threadIdx.x] += s[threadIdx.x+off];
    __syncthreads();
  }
  if (threadIdx.x==0) chunkSum[blockIdx.x] = s[0];
}

__global__ void k_scan_chunks(const int* __restrict__ chunkSum, int* __restrict__ chunkOff, int nChunks){
  __shared__ int s[256];
  int t = threadIdx.x;
  int v = (t < nChunks) ? chunkSum[t] : 0;
  s[t] = v; __syncthreads();
  for (int off=1; off<256; off<<=1){
    int u = (t>=off) ? s[t-off] : 0;
    __syncthreads();
    s[t] += u;
    __syncthreads();
  }
  if (t < nChunks) chunkOff[t] = s[t] - v;  // exclusive prefix of chunk sums
}

__global__ void k_local_scan(const int* __restrict__ deg, const int* __restrict__ chunkOff,
                             const int* __restrict__ batch,
                             int* __restrict__ rowStart, int* __restrict__ cursor,
                             float* __restrict__ dinv, int* __restrict__ gCnt){
  __shared__ int s[256];
  int t = threadIdx.x;
  int i = blockIdx.x*256 + t;
  int v = (i < N_NODES) ? deg[i] : 0;
  s[t] = v; __syncthreads();
  for (int off=1; off<256; off<<=1){
    int u = (t>=off) ? s[t-off] : 0;
    __syncthreads();
    s[t] += u;
    __syncthreads();
  }
  if (i < N_NODES){
    int rs = chunkOff[blockIdx.x] + s[t] - v;   // exclusive global prefix
    rowStart[i] = rs; cursor[i] = rs;
    dinv[i] = rsqrtf((float)v + 1.0f);          // deg = in-degree + 1 (ref adds 1.0)
    atomicAdd(&gCnt[batch[i]], 1);
  }
}

__global__ void k_bucket(const int* __restrict__ src, const int* __restrict__ dst,
                         int* __restrict__ cursor, int* __restrict__ eSrc){
  int e = blockIdx.x*256 + threadIdx.x;
  if (e < N_EDGES){
    int p = atomicAdd(&cursor[dst[e]], 1);
    eSrc[p] = src[e];
  }
}

// ---------- per-layer GEMM:  z[i][:] = (x[i] @ W) * dinv[i] ----------
// block = 256 = 4 waves; W (64KB) staged in LDS once per block; each wave does one row/iter,
// lane computes cols (lane, lane+64).

__global__ __launch_bounds__(256) void k_gemm(const float* __restrict__ xin,
            const int* __restrict__ feat, const float* __restrict__ emb,
            const float* __restrict__ W, const float* __restrict__ dinv,
            float* __restrict__ z){
  __shared__ float Wl[C*C];
  __shared__ float xl[4][C];
  int t = threadIdx.x;
  {
    const float4* W4 = (const float4*)W;
    float4* Wl4 = (float4*)Wl;
    #pragma unroll
    for (int i=0;i<16;i++) Wl4[t + i*256] = W4[t + i*256];
  }
  __syncthreads();
  int wave = t>>6, lane = t&63;
  for (int row0 = blockIdx.x*4; row0 < N_NODES; row0 += gridDim.x*4){
    int row = row0 + wave;
    if (row < N_NODES){
      const float* srcp = feat ? (emb + (size_t)feat[row]*C) : (xin + (size_t)row*C);
      float2 v = ((const float2*)srcp)[lane];
      ((float2*)xl[wave])[lane] = v;
    }
    __syncthreads();
    if (row < N_NODES){
      float a0=0.f, a1=0.f;
      #pragma unroll
      for (int k=0;k<C;k++){
        float xk = xl[wave][k];
        a0 = fmaf(xk, Wl[k*C + lane],      a0);
        a1 = fmaf(xk, Wl[k*C + lane + 64], a1);
      }
      float d = dinv[row];
      z[(size_t)row*C + lane]      = a0*d;
      z[(size_t)row*C + lane + 64] = a1*d;
    }
    __syncthreads();
  }
}

// ---------- aggregation (pure gather via CSR):  x[i] = relu(dinv[i]*(z[i]+sum z[src]) + b) ----------

__global__ void k_agg(const float* __restrict__ z, const int* __restrict__ eSrc,
                      const int* __restrict__ rowStart, const int* __restrict__ deg,
                      const float* __restrict__ dinv, const float* __restrict__ b,
                      float* __restrict__ xout){
  int node = blockIdx.x*2 + (threadIdx.x>>7);
  int c = threadIdx.x & 127;
  if (node >= N_NODES) return;
  int rs = rowStart[node], len = deg[node];
  float acc = z[(size_t)node*C + c];
  int k = 0;
  for (; k+4<=len; k+=4){
    int s0 = eSrc[rs+k], s1 = eSrc[rs+k+1], s2 = eSrc[rs+k+2], s3 = eSrc[rs+k+3];
    float v0 = z[(size_t)s0*C+c];
    float v1 = z[(size_t)s1*C+c];
    float v2 = z[(size_t)s2*C+c];
    float v3 = z[(size_t)s3*C+c];
    acc += v0; acc += v1; acc += v2; acc += v3;
  }
  for (; k<len; k++) acc += z[(size_t)eSrc[rs+k]*C + c];
  float v = fmaf(dinv[node], acc, b[c]);
  xout[(size_t)node*C + c] = fmaxf(v, 0.f);
}

// ---------- pooling: per-node dot with fcW, segment-sum by graph ----------

__global__ void k_pool(const float* __restrict__ x, const float* __restrict__ fcW,
                       const int* __restrict__ batch, float* __restrict__ gSum){
  int node = blockIdx.x*4 + (threadIdx.x>>6);
  int lane = threadIdx.x & 63;
  if (node >= N_NODES) return;
  float s = x[(size_t)node*C + lane]*fcW[lane] + x[(size_t)node*C + 64 + lane]*fcW[64+lane];
  #pragma unroll
  for (int off=32; off>0; off>>=1) s += __shfl_down(s, off);
  if (lane==0) atomicAdd(&gSum[batch[node]], s);
}

__global__ void k_final(const float* __restrict__ gSum, const int* __restrict__ gCnt,
                        const float* __restrict__ fcb, float* __restrict__ out){
  int g = threadIdx.x + blockIdx.x*256;
  if (g < N_GRAPHS) out[g] = gSum[g]/fmaxf((float)gCnt[g],1.0f) + fcb[0];
}

// ---------- launch ----------

extern "C" void kernel_launch(void* const* d_in, const int* in_sizes, int n_in,
                              void* d_out, int out_size, void* d_ws, size_t ws_size,
                              hipStream_t stream){
  const int* edge  = (const int*)d_in[0];
  const int* srcI  = edge;
  const int* dstI  = edge + N_EDGES;
  const int* feat  = (const int*)d_in[1];
  const int* batch = (const int*)d_in[2];
  const float* emb = (const float*)d_in[3];
  const float* W1  = (const float*)d_in[4];
  const float* b1  = (const float*)d_in[5];
  const float* W2  = (const float*)d_in[6];
  const float* b2  = (const float*)d_in[7];
  const float* W3  = (const float*)d_in[8];
  const float* b3  = (const float*)d_in[9];
  const float* fcW = (const float*)d_in[10];
  const float* fcb = (const float*)d_in[11];
  float* out = (float*)d_out;

  float* xBuf = (float*)d_ws;                       // 50000*128 f32
  float* zBuf = xBuf + (size_t)N_NODES*C;           // 50000*128 f32
  int* eSrc     = (int*)(zBuf + (size_t)N_NODES*C); // 800000
  int* rowStart = eSrc + N_EDGES;                   // 50000
  int* cursor   = rowStart + N_NODES;               // 50000
  int* deg      = cursor + N_NODES;                 // 50000
  float* dinv   = (float*)(deg + N_NODES);          // 50000
  int* chunkSum = (int*)(dinv + N_NODES);           // 256
  int* chunkOff = chunkSum + 256;                   // 256
  float* gSum   = (float*)(chunkOff + 256);         // 512
  int* gCnt     = (int*)(gSum + N_GRAPHS);          // 512

  hipMemsetAsync(deg, 0, N_NODES*sizeof(int), stream);
  hipMemsetAsync(gSum, 0, 2*N_GRAPHS*sizeof(float), stream);  // gSum + gCnt (contiguous)

  int nChunks = (N_NODES + 255)/256;  // 196 <= 256
  k_edge_deg   <<<(N_EDGES+255)/256, 256, 0, stream>>>(dstI, deg);
  k_chunk_sum  <<<nChunks, 256, 0, stream>>>(deg, chunkSum);
  k_scan_chunks<<<1, 256, 0, stream>>>(chunkSum, chunkOff, nChunks);
  k_local_scan <<<nChunks, 256, 0, stream>>>(deg, chunkOff, batch, rowStart, cursor, dinv, gCnt);
  k_bucket     <<<(N_EDGES+255)/256, 256, 0, stream>>>(srcI, dstI, cursor, eSrc);

  // layer 1 (embedding gather fused into GEMM)
  k_gemm<<<1024, 256, 0, stream>>>(nullptr, feat, emb, W1, dinv, zBuf);
  k_agg <<<N_NODES/2, 256, 0, stream>>>(zBuf, eSrc, rowStart, deg, dinv, b1, xBuf);
  // layer 2
  k_gemm<<<1024, 256, 0, stream>>>(xBuf, nullptr, nullptr, W2, dinv, zBuf);
  k_agg <<<N_NODES/2, 256, 0, stream>>>(zBuf, eSrc, rowStart, deg, dinv, b2, xBuf);
  // layer 3
  k_gemm<<<1024, 256, 0, stream>>>(xBuf, nullptr, nullptr, W3, dinv, zBuf);
  k_agg <<<N_NODES/2, 256, 0, stream>>>(zBuf, eSrc, rowStart, deg, dinv, b3, xBuf);

  k_pool <<<(N_NODES+3)/4, 256, 0, stream>>>(xBuf, fcW, batch, gSum);
  k_final<<<(N_GRAPHS+255)/256, 256, 0, stream>>>(gSum, gCnt, fcb, out);
}

// Round 2
// 413.877 us; speedup vs baseline: 1.5493x; 1.5493x over previous
//
#include <hip/hip_runtime.h>

#define N_NODES 50000
#define N_EDGES 800000
#define N_GRAPHS 512
#define C 128

// ---------- graph preprocessing ----------

__global__ void k_edge_deg(const int* __restrict__ dst, int* __restrict__ deg){
  int e = blockIdx.x*256 + threadIdx.x;
  if (e < N_EDGES) atomicAdd(&deg[dst[e]], 1);
}

__global__ void k_chunk_sum(const int* __restrict__ deg, int* __restrict__ chunkSum){
  __shared__ int s[256];
  int i = blockIdx.x*256 + threadIdx.x;
  int v = (i < N_NODES) ? deg[i] : 0;
  s[threadIdx.x] = v; __syncthreads();
  for (int off=128; off>0; off>>=1){
    if (threadIdx.x < off) s[threadIdx.x] += s[threadIdx.x+off];
    __syncthreads();
  }
  if (threadIdx.x==0) chunkSum[blockIdx.x] = s[0];
}

__global__ void k_scan_chunks(const int* __restrict__ chunkSum, int* __restrict__ chunkOff, int nChunks){
  __shared__ int s[256];
  int t = threadIdx.x;
  int v = (t < nChunks) ? chunkSum[t] : 0;
  s[t] = v; __syncthreads();
  for (int off=1; off<256; off<<=1){
    int u = (t>=off) ? s[t-off] : 0;
    __syncthreads();
    s[t] += u;
    __syncthreads();
  }
  if (t < nChunks) chunkOff[t] = s[t] - v;  // exclusive prefix of chunk sums
}

__global__ void k_local_scan(const int* __restrict__ deg, const int* __restrict__ chunkOff,
                             int* __restrict__ rowStart, int* __restrict__ cursor,
                             float* __restrict__ dinv){
  __shared__ int s[256];
  int t = threadIdx.x;
  int i = blockIdx.x*256 + t;
  int v = (i < N_NODES) ? deg[i] : 0;
  s[t] = v; __syncthreads();
  for (int off=1; off<256; off<<=1){
    int u = (t>=off) ? s[t-off] : 0;
    __syncthreads();
    s[t] += u;
    __syncthreads();
  }
  if (i < N_NODES){
    int rs = chunkOff[blockIdx.x] + s[t] - v;   // exclusive global prefix
    rowStart[i] = rs; cursor[i] = rs;
    dinv[i] = rsqrtf((float)v + 1.0f);          // deg = in-degree + 1 (ref adds 1.0)
  }
}

__global__ void k_bucket(const int* __restrict__ src, const int* __restrict__ dst,
                         int* __restrict__ cursor, int* __restrict__ eSrc){
  int e = blockIdx.x*256 + threadIdx.x;
  if (e < N_EDGES){
    int p = atomicAdd(&cursor[dst[e]], 1);
    eSrc[p] = src[e];
  }
}

// graph segment boundaries from sorted batch (no atomics)
__global__ void k_gstart(const int* __restrict__ batch, int* __restrict__ gStart){
  int i = blockIdx.x*256 + threadIdx.x;
  if (i >= N_NODES) return;
  int b = batch[i];
  int pb = (i==0) ? -1 : batch[i-1];
  for (int g=pb+1; g<=b; g++) gStart[g] = i;
  if (i == N_NODES-1){
    for (int g=b+1; g<=N_GRAPHS; g++) gStart[g] = N_NODES;
  }
}

// ---------- per-layer GEMM:  z[i][:] = (x[i] @ W) * dinv[i] ----------
// 256 thr = 4 waves; W (64KB) + 32-row x tile (16KB) in dynamic LDS.
// Each wave computes 8 rows; lane covers cols (2*lane, 2*lane+1). One W-read
// feeds 8 rows (16 FMA per ds_read_b64) -> LDS W-traffic /8 vs round-1.

#define GROWS 32

__global__ __launch_bounds__(256) void k_gemm(const float* __restrict__ xin,
            const int* __restrict__ feat, const float* __restrict__ emb,
            const float* __restrict__ W, const float* __restrict__ dinv,
            float* __restrict__ z){
  extern __shared__ float smem[];
  float* Wl = smem;          // C*C
  float* xl = smem + C*C;    // GROWS*C
  int t = threadIdx.x;
  {
    const float4* W4 = (const float4*)W;
    float4* Wl4 = (float4*)Wl;
    #pragma unroll
    for (int i=0;i<16;i++) Wl4[t + i*256] = W4[t + i*256];
  }
  int wave = t>>6, lane = t&63;
  for (int row0 = blockIdx.x*GROWS; row0 < N_NODES; row0 += gridDim.x*GROWS){
    // stage 32 rows (4096 floats = 1024 float4; 4 float4 per thread)
    #pragma unroll
    for (int i=0;i<4;i++){
      int idx = t + i*256;          // float4 index in tile
      int row = idx >> 5;           // /32 float4 per row
      int c4  = idx & 31;
      int gr  = row0 + row;
      if (gr < N_NODES){
        const float* srcp = feat ? (emb + (size_t)feat[gr]*C) : (xin + (size_t)gr*C);
        ((float4*)xl)[idx] = ((const float4*)srcp)[c4];
      }
    }
    __syncthreads();
    float2 acc[8];
    #pragma unroll
    for (int r=0;r<8;r++) acc[r] = make_float2(0.f,0.f);
    #pragma unroll 4
    for (int k=0;k<C;k++){
      float2 w = *(const float2*)&Wl[k*C + 2*lane];
      #pragma unroll
      for (int r=0;r<8;r++){
        float xk = xl[(wave*8+r)*C + k];
        acc[r].x = fmaf(xk, w.x, acc[r].x);
        acc[r].y = fmaf(xk, w.y, acc[r].y);
      }
    }
    #pragma unroll
    for (int r=0;r<8;r++){
      int row = row0 + wave*8 + r;
      if (row < N_NODES){
        float d = dinv[row];
        *(float2*)&z[(size_t)row*C + 2*lane] = make_float2(acc[r].x*d, acc[r].y*d);
      }
    }
    __syncthreads();
  }
}

// ---------- aggregation (pure gather via CSR) ----------
// wave per node; lane covers cols (2*lane, 2*lane+1) via float2.
// layers 1-2: xout = relu(dinv*(z+sum z[src]) + b)
// layer 3 (dots != null): per-node dot with fcW instead of writing xout.

__global__ __launch_bounds__(256) void k_agg(const float* __restrict__ z, const int* __restrict__ eSrc,
                      const int* __restrict__ rowStart, const int* __restrict__ deg,
                      const float* __restrict__ dinv, const float* __restrict__ b,
                      float* __restrict__ xout, const float* __restrict__ fcW,
                      float* __restrict__ dots){
  int node = blockIdx.x*4 + (threadIdx.x>>6);
  int lane = threadIdx.x & 63;
  if (node >= N_NODES) return;
  int rs = rowStart[node], len = deg[node];
  float2 a = ((const float2*)(z + (size_t)node*C))[lane];
  int k = 0;
  for (; k+4<=len; k+=4){
    int s0 = eSrc[rs+k], s1 = eSrc[rs+k+1], s2 = eSrc[rs+k+2], s3 = eSrc[rs+k+3];
    float2 v0 = ((const float2*)(z+(size_t)s0*C))[lane];
    float2 v1 = ((const float2*)(z+(size_t)s1*C))[lane];
    float2 v2 = ((const float2*)(z+(size_t)s2*C))[lane];
    float2 v3 = ((const float2*)(z+(size_t)s3*C))[lane];
    a.x += v0.x + v1.x + v2.x + v3.x;
    a.y += v0.y + v1.y + v2.y + v3.y;
  }
  for (; k<len; k++){
    float2 v = ((const float2*)(z+(size_t)eSrc[rs+k]*C))[lane];
    a.x += v.x; a.y += v.y;
  }
  float dn = dinv[node];
  float2 bb = ((const float2*)b)[lane];
  float v0 = fmaxf(fmaf(dn, a.x, bb.x), 0.f);
  float v1 = fmaxf(fmaf(dn, a.y, bb.y), 0.f);
  if (dots){
    float2 fw = ((const float2*)fcW)[lane];
    float s = v0*fw.x + v1*fw.y;
    #pragma unroll
    for (int off=32; off>0; off>>=1) s += __shfl_down(s, off);
    if (lane==0) dots[node] = s;
  } else {
    ((float2*)(xout + (size_t)node*C))[lane] = make_float2(v0, v1);
  }
}

// ---------- pooling: per-graph segment mean of dots ----------

__global__ void k_pool_seg(const float* __restrict__ dots, const int* __restrict__ gStart,
                           const float* __restrict__ fcb, float* __restrict__ out){
  __shared__ float s[256];
  int g = blockIdx.x;
  int st = gStart[g], en = gStart[g+1];
  float acc = 0.f;
  for (int i = st + threadIdx.x; i < en; i += 256) acc += dots[i];
  s[threadIdx.x] = acc; __syncthreads();
  for (int off=128; off>0; off>>=1){
    if (threadIdx.x < off) s[threadIdx.x] += s[threadIdx.x+off];
    __syncthreads();
  }
  if (threadIdx.x==0) out[g] = s[0]/fmaxf((float)(en-st),1.0f) + fcb[0];
}

// ---------- launch ----------

extern "C" void kernel_launch(void* const* d_in, const int* in_sizes, int n_in,
                              void* d_out, int out_size, void* d_ws, size_t ws_size,
                              hipStream_t stream){
  const int* edge  = (const int*)d_in[0];
  const int* srcI  = edge;
  const int* dstI  = edge + N_EDGES;
  const int* feat  = (const int*)d_in[1];
  const int* batch = (const int*)d_in[2];
  const float* emb = (const float*)d_in[3];
  const float* W1  = (const float*)d_in[4];
  const float* b1  = (const float*)d_in[5];
  const float* W2  = (const float*)d_in[6];
  const float* b2  = (const float*)d_in[7];
  const float* W3  = (const float*)d_in[8];
  const float* b3  = (const float*)d_in[9];
  const float* fcW = (const float*)d_in[10];
  const float* fcb = (const float*)d_in[11];
  float* out = (float*)d_out;

  float* xBuf = (float*)d_ws;                       // 50000*128 f32
  float* zBuf = xBuf + (size_t)N_NODES*C;           // 50000*128 f32
  int* eSrc     = (int*)(zBuf + (size_t)N_NODES*C); // 800000
  int* rowStart = eSrc + N_EDGES;                   // 50000
  int* cursor   = rowStart + N_NODES;               // 50000
  int* deg      = cursor + N_NODES;                 // 50000
  float* dinv   = (float*)(deg + N_NODES);          // 50000
  int* chunkSum = (int*)(dinv + N_NODES);           // 256
  int* chunkOff = chunkSum + 256;                   // 256
  int* gStart   = chunkOff + 256;                   // 513
  float* dots   = (float*)(gStart + 520);           // 50000

  hipMemsetAsync(deg, 0, N_NODES*sizeof(int), stream);

  int nChunks = (N_NODES + 255)/256;  // 196 <= 256
  k_edge_deg   <<<(N_EDGES+255)/256, 256, 0, stream>>>(dstI, deg);
  k_chunk_sum  <<<nChunks, 256, 0, stream>>>(deg, chunkSum);
  k_scan_chunks<<<1, 256, 0, stream>>>(chunkSum, chunkOff, nChunks);
  k_local_scan <<<nChunks, 256, 0, stream>>>(deg, chunkOff, rowStart, cursor, dinv);
  k_gstart     <<<nChunks, 256, 0, stream>>>(batch, gStart);
  k_bucket     <<<(N_EDGES+255)/256, 256, 0, stream>>>(srcI, dstI, cursor, eSrc);

  size_t gemmLds = (size_t)(C*C + GROWS*C)*sizeof(float);  // 80 KB
  // layer 1 (embedding gather fused into GEMM)
  k_gemm<<<512, 256, gemmLds, stream>>>(nullptr, feat, emb, W1, dinv, zBuf);
  k_agg <<<(N_NODES+3)/4, 256, 0, stream>>>(zBuf, eSrc, rowStart, deg, dinv, b1, xBuf, nullptr, nullptr);
  // layer 2
  k_gemm<<<512, 256, gemmLds, stream>>>(xBuf, nullptr, nullptr, W2, dinv, zBuf);
  k_agg <<<(N_NODES+3)/4, 256, 0, stream>>>(zBuf, eSrc, rowStart, deg, dinv, b2, xBuf, nullptr, nullptr);
  // layer 3 (fused fcW dot, no xout write)
  k_gemm<<<512, 256, gemmLds, stream>>>(xBuf, nullptr, nullptr, W3, dinv, zBuf);
  k_agg <<<(N_NODES+3)/4, 256, 0, stream>>>(zBuf, eSrc, rowStart, deg, dinv, b3, nullptr, fcW, dots);

  k_pool_seg<<<N_GRAPHS, 256, 0, stream>>>(dots, gStart, fcb, out);
}

// Round 3
// 354.362 us; speedup vs baseline: 1.8095x; 1.1680x over previous
//
#include <hip/hip_runtime.h>
#include <hip/hip_fp16.h>

#define N_NODES 50000
#define N_EDGES 800000
#define N_GRAPHS 512
#define C 128

// ---------- graph preprocessing ----------

__global__ void k_edge_deg(const int* __restrict__ dst, int* __restrict__ deg){
  int e = blockIdx.x*256 + threadIdx.x;
  if (e < N_EDGES) atomicAdd(&deg[dst[e]], 1);
}

__global__ void k_chunk_sum(const int* __restrict__ deg, int* __restrict__ chunkSum){
  __shared__ int s[256];
  int i = blockIdx.x*256 + threadIdx.x;
  int v = (i < N_NODES) ? deg[i] : 0;
  s[threadIdx.x] = v; __syncthreads();
  for (int off=128; off>0; off>>=1){
    if (threadIdx.x < off) s[threadIdx.x] += s[threadIdx.x+off];
    __syncthreads();
  }
  if (threadIdx.x==0) chunkSum[blockIdx.x] = s[0];
}

__global__ void k_scan_chunks(const int* __restrict__ chunkSum, int* __restrict__ chunkOff, int nChunks){
  __shared__ int s[256];
  int t = threadIdx.x;
  int v = (t < nChunks) ? chunkSum[t] : 0;
  s[t] = v; __syncthreads();
  for (int off=1; off<256; off<<=1){
    int u = (t>=off) ? s[t-off] : 0;
    __syncthreads();
    s[t] += u;
    __syncthreads();
  }
  if (t < nChunks) chunkOff[t] = s[t] - v;  // exclusive prefix of chunk sums
}

__global__ void k_local_scan(const int* __restrict__ deg, const int* __restrict__ chunkOff,
                             int* __restrict__ rowStart, int* __restrict__ cursor,
                             float* __restrict__ dinv){
  __shared__ int s[256];
  int t = threadIdx.x;
  int i = blockIdx.x*256 + t;
  int v = (i < N_NODES) ? deg[i] : 0;
  s[t] = v; __syncthreads();
  for (int off=1; off<256; off<<=1){
    int u = (t>=off) ? s[t-off] : 0;
    __syncthreads();
    s[t] += u;
    __syncthreads();
  }
  if (i < N_NODES){
    int rs = chunkOff[blockIdx.x] + s[t] - v;   // exclusive global prefix
    rowStart[i] = rs; cursor[i] = rs;
    dinv[i] = rsqrtf((float)v + 1.0f);          // deg = in-degree + 1 (ref adds 1.0)
  }
}

__global__ void k_bucket(const int* __restrict__ src, const int* __restrict__ dst,
                         int* __restrict__ cursor, int* __restrict__ eSrc){
  int e = blockIdx.x*256 + threadIdx.x;
  if (e < N_EDGES){
    int p = atomicAdd(&cursor[dst[e]], 1);
    eSrc[p] = src[e];
  }
}

// graph segment boundaries from sorted batch (no atomics)
__global__ void k_gstart(const int* __restrict__ batch, int* __restrict__ gStart){
  int i = blockIdx.x*256 + threadIdx.x;
  if (i >= N_NODES) return;
  int b = batch[i];
  int pb = (i==0) ? -1 : batch[i-1];
  for (int g=pb+1; g<=b; g++) gStart[g] = i;
  if (i == N_NODES-1){
    for (int g=b+1; g<=N_GRAPHS; g++) gStart[g] = N_NODES;
  }
}

// ---------- per-layer GEMM:  zh[i][:] = fp16( (x[i] @ W) * dinv[i] ) ----------
// 256 thr = 4 waves. Wave computes 8 rows x 128 cols: lane&31 -> col group of 4
// (float4 W read, 2-way lane alias = free), lane>>5 -> which 4 rows. Per k:
// 1 ds_read_b128 + 4 ds_read_b32 feed 16 FMA (76% FMA density).

#define GROWS 32

__global__ __launch_bounds__(256) void k_gemm(const float* __restrict__ xin,
            const int* __restrict__ feat, const float* __restrict__ emb,
            const float* __restrict__ W, const float* __restrict__ dinv,
            __half* __restrict__ zh){
  extern __shared__ float smem[];
  float* Wl = smem;          // C*C
  float* xl = smem + C*C;    // GROWS*C
  int t = threadIdx.x;
  {
    const float4* W4 = (const float4*)W;
    float4* Wl4 = (float4*)Wl;
    #pragma unroll
    for (int i=0;i<16;i++) Wl4[t + i*256] = W4[t + i*256];
  }
  int wave = t>>6, lane = t&63;
  int cg = lane & 31;        // cols 4*cg .. 4*cg+3
  int rh = lane >> 5;        // row half
  int rbase = wave*8 + rh*4;
  for (int row0 = blockIdx.x*GROWS; row0 < N_NODES; row0 += gridDim.x*GROWS){
    // stage 32 rows (4096 floats = 1024 float4; 4 float4 per thread)
    #pragma unroll
    for (int i=0;i<4;i++){
      int idx = t + i*256;          // float4 index in tile
      int row = idx >> 5;
      int c4  = idx & 31;
      int gr  = row0 + row;
      if (gr < N_NODES){
        const float* srcp = feat ? (emb + (size_t)feat[gr]*C) : (xin + (size_t)gr*C);
        ((float4*)xl)[idx] = ((const float4*)srcp)[c4];
      }
    }
    __syncthreads();
    float4 acc[4];
    #pragma unroll
    for (int r=0;r<4;r++) acc[r] = make_float4(0.f,0.f,0.f,0.f);
    #pragma unroll 4
    for (int k=0;k<C;k++){
      float4 w = *(const float4*)&Wl[k*C + 4*cg];
      #pragma unroll
      for (int r=0;r<4;r++){
        float xk = xl[(rbase + r)*C + k];
        acc[r].x = fmaf(xk, w.x, acc[r].x);
        acc[r].y = fmaf(xk, w.y, acc[r].y);
        acc[r].z = fmaf(xk, w.z, acc[r].z);
        acc[r].w = fmaf(xk, w.w, acc[r].w);
      }
    }
    #pragma unroll
    for (int r=0;r<4;r++){
      int row = row0 + rbase + r;
      if (row < N_NODES){
        float d = dinv[row];
        __half2 h0 = __float22half2_rn(make_float2(acc[r].x*d, acc[r].y*d));
        __half2 h1 = __float22half2_rn(make_float2(acc[r].z*d, acc[r].w*d));
        __half2* zp = (__half2*)(zh + (size_t)row*C + 4*cg);
        zp[0] = h0; zp[1] = h1;
      }
    }
    __syncthreads();
  }
}

// ---------- aggregation (pure gather via CSR, fp16 operand, fp32 accum) ----------
// wave per node; lane covers cols (2*lane, 2*lane+1) via half2.
// layers 1-2: xout = relu(dinv*(z+sum z[src]) + b)
// layer 3 (dots != null): per-node dot with fcW instead of writing xout.

__global__ __launch_bounds__(256) void k_agg(const __half* __restrict__ zh, const int* __restrict__ eSrc,
                      const int* __restrict__ rowStart, const int* __restrict__ deg,
                      const float* __restrict__ dinv, const float* __restrict__ b,
                      float* __restrict__ xout, const float* __restrict__ fcW,
                      float* __restrict__ dots){
  int node = blockIdx.x*4 + (threadIdx.x>>6);
  int lane = threadIdx.x & 63;
  if (node >= N_NODES) return;
  int rs = rowStart[node], len = deg[node];
  const __half2* zb = (const __half2*)zh;   // row stride 64 half2
  float2 a = __half22float2(zb[(size_t)node*64 + lane]);
  int k = 0;
  for (; k+4<=len; k+=4){
    int s0 = eSrc[rs+k], s1 = eSrc[rs+k+1], s2 = eSrc[rs+k+2], s3 = eSrc[rs+k+3];
    float2 v0 = __half22float2(zb[(size_t)s0*64 + lane]);
    float2 v1 = __half22float2(zb[(size_t)s1*64 + lane]);
    float2 v2 = __half22float2(zb[(size_t)s2*64 + lane]);
    float2 v3 = __half22float2(zb[(size_t)s3*64 + lane]);
    a.x += v0.x + v1.x + v2.x + v3.x;
    a.y += v0.y + v1.y + v2.y + v3.y;
  }
  for (; k<len; k++){
    float2 v = __half22float2(zb[(size_t)eSrc[rs+k]*64 + lane]);
    a.x += v.x; a.y += v.y;
  }
  float dn = dinv[node];
  float2 bb = ((const float2*)b)[lane];
  float v0 = fmaxf(fmaf(dn, a.x, bb.x), 0.f);
  float v1 = fmaxf(fmaf(dn, a.y, bb.y), 0.f);
  if (dots){
    float2 fw = ((const float2*)fcW)[lane];
    float s = v0*fw.x + v1*fw.y;
    #pragma unroll
    for (int off=32; off>0; off>>=1) s += __shfl_down(s, off);
    if (lane==0) dots[node] = s;
  } else {
    ((float2*)(xout + (size_t)node*C))[lane] = make_float2(v0, v1);
  }
}

// ---------- pooling: per-graph segment mean of dots ----------

__global__ void k_pool_seg(const float* __restrict__ dots, const int* __restrict__ gStart,
                           const float* __restrict__ fcb, float* __restrict__ out){
  __shared__ float s[256];
  int g = blockIdx.x;
  int st = gStart[g], en = gStart[g+1];
  float acc = 0.f;
  for (int i = st + threadIdx.x; i < en; i += 256) acc += dots[i];
  s[threadIdx.x] = acc; __syncthreads();
  for (int off=128; off>0; off>>=1){
    if (threadIdx.x < off) s[threadIdx.x] += s[threadIdx.x+off];
    __syncthreads();
  }
  if (threadIdx.x==0) out[g] = s[0]/fmaxf((float)(en-st),1.0f) + fcb[0];
}

// ---------- launch ----------

extern "C" void kernel_launch(void* const* d_in, const int* in_sizes, int n_in,
                              void* d_out, int out_size, void* d_ws, size_t ws_size,
                              hipStream_t stream){
  const int* edge  = (const int*)d_in[0];
  const int* srcI  = edge;
  const int* dstI  = edge + N_EDGES;
  const int* feat  = (const int*)d_in[1];
  const int* batch = (const int*)d_in[2];
  const float* emb = (const float*)d_in[3];
  const float* W1  = (const float*)d_in[4];
  const float* b1  = (const float*)d_in[5];
  const float* W2  = (const float*)d_in[6];
  const float* b2  = (const float*)d_in[7];
  const float* W3  = (const float*)d_in[8];
  const float* b3  = (const float*)d_in[9];
  const float* fcW = (const float*)d_in[10];
  const float* fcb = (const float*)d_in[11];
  float* out = (float*)d_out;

  float* xBuf = (float*)d_ws;                       // 50000*128 f32
  __half* zh  = (__half*)(xBuf + (size_t)N_NODES*C);// 50000*128 f16
  float* zpad = (float*)zh + (size_t)N_NODES*C/2;   // end of zh region
  int* eSrc     = (int*)zpad;                       // 800000
  int* rowStart = eSrc + N_EDGES;                   // 50000
  int* cursor   = rowStart + N_NODES;               // 50000
  int* deg      = cursor + N_NODES;                 // 50000
  float* dinv   = (float*)(deg + N_NODES);          // 50000
  int* chunkSum = (int*)(dinv + N_NODES);           // 256
  int* chunkOff = chunkSum + 256;                   // 256
  int* gStart   = chunkOff + 256;                   // 513
  float* dots   = (float*)(gStart + 520);           // 50000

  hipMemsetAsync(deg, 0, N_NODES*sizeof(int), stream);

  int nChunks = (N_NODES + 255)/256;  // 196 <= 256
  k_edge_deg   <<<(N_EDGES+255)/256, 256, 0, stream>>>(dstI, deg);
  k_chunk_sum  <<<nChunks, 256, 0, stream>>>(deg, chunkSum);
  k_scan_chunks<<<1, 256, 0, stream>>>(chunkSum, chunkOff, nChunks);
  k_local_scan <<<nChunks, 256, 0, stream>>>(deg, chunkOff, rowStart, cursor, dinv);
  k_gstart     <<<nChunks, 256, 0, stream>>>(batch, gStart);
  k_bucket     <<<(N_EDGES+255)/256, 256, 0, stream>>>(srcI, dstI, cursor, eSrc);

  size_t gemmLds = (size_t)(C*C + GROWS*C)*sizeof(float);  // 80 KB
  // layer 1 (embedding gather fused into GEMM)
  k_gemm<<<512, 256, gemmLds, stream>>>(nullptr, feat, emb, W1, dinv, zh);
  k_agg <<<(N_NODES+3)/4, 256, 0, stream>>>(zh, eSrc, rowStart, deg, dinv, b1, xBuf, nullptr, nullptr);
  // layer 2
  k_gemm<<<512, 256, gemmLds, stream>>>(xBuf, nullptr, nullptr, W2, dinv, zh);
  k_agg <<<(N_NODES+3)/4, 256, 0, stream>>>(zh, eSrc, rowStart, deg, dinv, b2, xBuf, nullptr, nullptr);
  // layer 3 (fused fcW dot, no xout write)
  k_gemm<<<512, 256, gemmLds, stream>>>(xBuf, nullptr, nullptr, W3, dinv, zh);
  k_agg <<<(N_NODES+3)/4, 256, 0, stream>>>(zh, eSrc, rowStart, deg, dinv, b3, nullptr, fcW, dots);

  k_pool_seg<<<N_GRAPHS, 256, 0, stream>>>(dots, gStart, fcb, out);
}

// Round 4
// 285.316 us; speedup vs baseline: 2.2474x; 1.2420x over previous
//
#include <hip/hip_runtime.h>
#include <hip/hip_fp16.h>

#define N_NODES 50000
#define N_EDGES 800000
#define N_GRAPHS 512
#define C 128

typedef __attribute__((ext_vector_type(8))) short short8v;
typedef __attribute__((ext_vector_type(4))) float f32x4;

__device__ __forceinline__ unsigned short f2bf(float f){
  unsigned u = __builtin_bit_cast(unsigned, f);
  unsigned r = u + 0x7FFFu + ((u >> 16) & 1u);
  return (unsigned short)(r >> 16);
}
__device__ __forceinline__ float bf2f(unsigned short h){
  unsigned u = ((unsigned)h) << 16;
  return __builtin_bit_cast(float, u);
}

// ---------- graph preprocessing ----------

__global__ void k_edge_deg(const int* __restrict__ dst, int* __restrict__ deg){
  int e = blockIdx.x*256 + threadIdx.x;
  if (e < N_EDGES) atomicAdd(&deg[dst[e]], 1);
}

__global__ void k_chunk_sum(const int* __restrict__ deg, int* __restrict__ chunkSum){
  __shared__ int s[256];
  int i = blockIdx.x*256 + threadIdx.x;
  int v = (i < N_NODES) ? deg[i] : 0;
  s[threadIdx.x] = v; __syncthreads();
  for (int off=128; off>0; off>>=1){
    if (threadIdx.x < off) s[threadIdx.x] += s[threadIdx.x+off];
    __syncthreads();
  }
  if (threadIdx.x==0) chunkSum[blockIdx.x] = s[0];
}

__global__ void k_scan_chunks(const int* __restrict__ chunkSum, int* __restrict__ chunkOff, int nChunks){
  __shared__ int s[256];
  int t = threadIdx.x;
  int v = (t < nChunks) ? chunkSum[t] : 0;
  s[t] = v; __syncthreads();
  for (int off=1; off<256; off<<=1){
    int u = (t>=off) ? s[t-off] : 0;
    __syncthreads();
    s[t] += u;
    __syncthreads();
  }
  if (t < nChunks) chunkOff[t] = s[t] - v;
}

__global__ void k_local_scan(const int* __restrict__ deg, const int* __restrict__ chunkOff,
                             int* __restrict__ rowStart, int* __restrict__ cursor,
                             float* __restrict__ dinv){
  __shared__ int s[256];
  int t = threadIdx.x;
  int i = blockIdx.x*256 + t;
  int v = (i < N_NODES) ? deg[i] : 0;
  s[t] = v; __syncthreads();
  for (int off=1; off<256; off<<=1){
    int u = (t>=off) ? s[t-off] : 0;
    __syncthreads();
    s[t] += u;
    __syncthreads();
  }
  if (i < N_NODES){
    int rs = chunkOff[blockIdx.x] + s[t] - v;
    rowStart[i] = rs; cursor[i] = rs;
    dinv[i] = rsqrtf((float)v + 1.0f);
  }
}

__global__ void k_bucket(const int* __restrict__ src, const int* __restrict__ dst,
                         int* __restrict__ cursor, int* __restrict__ eSrc){
  int e = blockIdx.x*256 + threadIdx.x;
  if (e < N_EDGES){
    int p = atomicAdd(&cursor[dst[e]], 1);
    eSrc[p] = src[e];
  }
}

__global__ void k_gstart(const int* __restrict__ batch, int* __restrict__ gStart){
  int i = blockIdx.x*256 + threadIdx.x;
  if (i >= N_NODES) return;
  int b = batch[i];
  int pb = (i==0) ? -1 : batch[i-1];
  for (int g=pb+1; g<=b; g++) gStart[g] = i;
  if (i == N_NODES-1){
    for (int g=b+1; g<=N_GRAPHS; g++) gStart[g] = N_NODES;
  }
}

// ---------- W prepack into MFMA B-fragment layout (hi + lo bf16 split) ----------
// B[k][c]: tile (kt,ct); lane l holds col c=ct*16+(l&15), k = kt*32 + (l>>4)*8 + i.
// Same k-map f(q,i)=q*8+i is used for the A-fragment, so any deviation from the
// HW's internal k-order cancels (same permutation on both operands of the K-sum).

__global__ void k_prepack(const float* __restrict__ W, short* __restrict__ Bh, short* __restrict__ Bl){
  int t = blockIdx.x*256 + threadIdx.x;   // 2048 = 32 tiles * 64 lanes
  if (t >= 2048) return;
  int lane = t & 63, tile = t >> 6;       // tile = kt*8 + ct
  int kt = tile >> 3, ct = tile & 7;
  int q = lane >> 4, c = ct*16 + (lane & 15);
  #pragma unroll
  for (int i=0;i<8;i++){
    int k = kt*32 + q*8 + i;
    float w = W[k*C + c];
    unsigned short hh = f2bf(w);
    unsigned short ll = f2bf(w - bf2f(hh));
    Bh[(size_t)(tile*64 + lane)*8 + i] = (short)hh;
    Bl[(size_t)(tile*64 + lane)*8 + i] = (short)ll;
  }
}

// ---------- MFMA GEMM: zh[i][:] = fp16( (x[i] @ W) * dinv[i] ) ----------
// 1 wave = 16 rows x 128 cols. A-frags from global (x read exactly once),
// B-frags (prepacked) from L1/L2. 3 MFMA per (kt,ct): xh*Wh + xl*Wh + xh*Wl.

__global__ __launch_bounds__(256) void k_gemm_mfma(const float* __restrict__ xin,
            const int* __restrict__ feat, const float* __restrict__ emb,
            const short* __restrict__ Bh, const short* __restrict__ Bl,
            const float* __restrict__ dinv, __half* __restrict__ zh){
  int lane = threadIdx.x & 63;
  int rt = blockIdx.x*4 + (threadIdx.x >> 6);
  if (rt*16 >= N_NODES) return;
  int r15 = lane & 15, q = lane >> 4;
  int row = rt*16 + r15;
  const float* xrow = feat ? (emb + (size_t)feat[row]*C) : (xin + (size_t)row*C);

  f32x4 acc[8];
  #pragma unroll
  for (int ct=0;ct<8;ct++) acc[ct] = (f32x4){0.f,0.f,0.f,0.f};

  const short8v* BH = (const short8v*)Bh;
  const short8v* BL = (const short8v*)Bl;

  #pragma unroll
  for (int kt=0; kt<4; kt++){
    float4 xa = *(const float4*)(xrow + kt*32 + q*8);
    float4 xb = *(const float4*)(xrow + kt*32 + q*8 + 4);
    float xv[8] = {xa.x, xa.y, xa.z, xa.w, xb.x, xb.y, xb.z, xb.w};
    short8v ah, al;
    #pragma unroll
    for (int i=0;i<8;i++){
      unsigned short h = f2bf(xv[i]);
      ah[i] = (short)h;
      al[i] = (short)f2bf(xv[i] - bf2f(h));
    }
    #pragma unroll
    for (int ct=0; ct<8; ct++){
      short8v bh = BH[(kt*8+ct)*64 + lane];
      short8v bl = BL[(kt*8+ct)*64 + lane];
      acc[ct] = __builtin_amdgcn_mfma_f32_16x16x32_bf16(ah, bh, acc[ct], 0, 0, 0);
      acc[ct] = __builtin_amdgcn_mfma_f32_16x16x32_bf16(al, bh, acc[ct], 0, 0, 0);
      acc[ct] = __builtin_amdgcn_mfma_f32_16x16x32_bf16(ah, bl, acc[ct], 0, 0, 0);
    }
  }

  // C/D layout (verified m89): col = ct*16 + (lane&15), row = rt*16 + q*4 + j
  #pragma unroll
  for (int j=0;j<4;j++){
    int rz = rt*16 + q*4 + j;
    float d = dinv[rz];
    #pragma unroll
    for (int ct=0; ct<8; ct++){
      zh[(size_t)rz*C + ct*16 + r15] = __float2half(acc[ct][j] * d);
    }
  }
}

// ---------- aggregation (pure gather via CSR, fp16 operand, fp32 accum) ----------

__global__ __launch_bounds__(256) void k_agg(const __half* __restrict__ zh, const int* __restrict__ eSrc,
                      const int* __restrict__ rowStart, const int* __restrict__ deg,
                      const float* __restrict__ dinv, const float* __restrict__ b,
                      float* __restrict__ xout, const float* __restrict__ fcW,
                      float* __restrict__ dots){
  int node = blockIdx.x*4 + (threadIdx.x>>6);
  int lane = threadIdx.x & 63;
  if (node >= N_NODES) return;
  int rs = rowStart[node], len = deg[node];
  const __half2* zb = (const __half2*)zh;   // row stride 64 half2
  float2 a = __half22float2(zb[(size_t)node*64 + lane]);
  int k = 0;
  for (; k+4<=len; k+=4){
    int s0 = eSrc[rs+k], s1 = eSrc[rs+k+1], s2 = eSrc[rs+k+2], s3 = eSrc[rs+k+3];
    float2 v0 = __half22float2(zb[(size_t)s0*64 + lane]);
    float2 v1 = __half22float2(zb[(size_t)s1*64 + lane]);
    float2 v2 = __half22float2(zb[(size_t)s2*64 + lane]);
    float2 v3 = __half22float2(zb[(size_t)s3*64 + lane]);
    a.x += v0.x + v1.x + v2.x + v3.x;
    a.y += v0.y + v1.y + v2.y + v3.y;
  }
  for (; k<len; k++){
    float2 v = __half22float2(zb[(size_t)eSrc[rs+k]*64 + lane]);
    a.x += v.x; a.y += v.y;
  }
  float dn = dinv[node];
  float2 bb = ((const float2*)b)[lane];
  float v0 = fmaxf(fmaf(dn, a.x, bb.x), 0.f);
  float v1 = fmaxf(fmaf(dn, a.y, bb.y), 0.f);
  if (dots){
    float2 fw = ((const float2*)fcW)[lane];
    float s = v0*fw.x + v1*fw.y;
    #pragma unroll
    for (int off=32; off>0; off>>=1) s += __shfl_down(s, off);
    if (lane==0) dots[node] = s;
  } else {
    ((float2*)(xout + (size_t)node*C))[lane] = make_float2(v0, v1);
  }
}

// ---------- pooling ----------

__global__ void k_pool_seg(const float* __restrict__ dots, const int* __restrict__ gStart,
                           const float* __restrict__ fcb, float* __restrict__ out){
  __shared__ float s[256];
  int g = blockIdx.x;
  int st = gStart[g], en = gStart[g+1];
  float acc = 0.f;
  for (int i = st + threadIdx.x; i < en; i += 256) acc += dots[i];
  s[threadIdx.x] = acc; __syncthreads();
  for (int off=128; off>0; off>>=1){
    if (threadIdx.x < off) s[threadIdx.x] += s[threadIdx.x+off];
    __syncthreads();
  }
  if (threadIdx.x==0) out[g] = s[0]/fmaxf((float)(en-st),1.0f) + fcb[0];
}

// ---------- launch ----------

extern "C" void kernel_launch(void* const* d_in, const int* in_sizes, int n_in,
                              void* d_out, int out_size, void* d_ws, size_t ws_size,
                              hipStream_t stream){
  const int* edge  = (const int*)d_in[0];
  const int* srcI  = edge;
  const int* dstI  = edge + N_EDGES;
  const int* feat  = (const int*)d_in[1];
  const int* batch = (const int*)d_in[2];
  const float* emb = (const float*)d_in[3];
  const float* W1  = (const float*)d_in[4];
  const float* b1  = (const float*)d_in[5];
  const float* W2  = (const float*)d_in[6];
  const float* b2  = (const float*)d_in[7];
  const float* W3  = (const float*)d_in[8];
  const float* b3  = (const float*)d_in[9];
  const float* fcW = (const float*)d_in[10];
  const float* fcb = (const float*)d_in[11];
  float* out = (float*)d_out;

  float* xBuf = (float*)d_ws;                       // 50000*128 f32
  __half* zh  = (__half*)(xBuf + (size_t)N_NODES*C);// 50000*128 f16
  float* zpad = (float*)zh + (size_t)N_NODES*C/2;
  int* eSrc     = (int*)zpad;                       // 800000
  int* rowStart = eSrc + N_EDGES;                   // 50000
  int* cursor   = rowStart + N_NODES;               // 50000
  int* deg      = cursor + N_NODES;                 // 50000
  float* dinv   = (float*)(deg + N_NODES);          // 50000
  int* chunkSum = (int*)(dinv + N_NODES);           // 256
  int* chunkOff = chunkSum + 256;                   // 256
  int* gStart   = chunkOff + 256;                   // 513 (+pad)
  float* dots   = (float*)(gStart + 520);           // 50000
  short* Bpack  = (short*)(dots + N_NODES);         // 6 * 16384 shorts
  short* Bh1 = Bpack,           * Bl1 = Bpack + 16384;
  short* Bh2 = Bpack + 2*16384, * Bl2 = Bpack + 3*16384;
  short* Bh3 = Bpack + 4*16384, * Bl3 = Bpack + 5*16384;

  hipMemsetAsync(deg, 0, N_NODES*sizeof(int), stream);

  int nChunks = (N_NODES + 255)/256;  // 196
  k_edge_deg   <<<(N_EDGES+255)/256, 256, 0, stream>>>(dstI, deg);
  k_chunk_sum  <<<nChunks, 256, 0, stream>>>(deg, chunkSum);
  k_scan_chunks<<<1, 256, 0, stream>>>(chunkSum, chunkOff, nChunks);
  k_local_scan <<<nChunks, 256, 0, stream>>>(deg, chunkOff, rowStart, cursor, dinv);
  k_gstart     <<<nChunks, 256, 0, stream>>>(batch, gStart);
  k_bucket     <<<(N_EDGES+255)/256, 256, 0, stream>>>(srcI, dstI, cursor, eSrc);

  k_prepack<<<8, 256, 0, stream>>>(W1, Bh1, Bl1);
  k_prepack<<<8, 256, 0, stream>>>(W2, Bh2, Bl2);
  k_prepack<<<8, 256, 0, stream>>>(W3, Bh3, Bl3);

  int gemmBlocks = (N_NODES/16 + 3)/4 + 1;   // 3125 row-tiles / 4 waves per block
  // layer 1 (embedding gather fused)
  k_gemm_mfma<<<gemmBlocks, 256, 0, stream>>>(nullptr, feat, emb, Bh1, Bl1, dinv, zh);
  k_agg <<<(N_NODES+3)/4, 256, 0, stream>>>(zh, eSrc, rowStart, deg, dinv, b1, xBuf, nullptr, nullptr);
  // layer 2
  k_gemm_mfma<<<gemmBlocks, 256, 0, stream>>>(xBuf, nullptr, nullptr, Bh2, Bl2, dinv, zh);
  k_agg <<<(N_NODES+3)/4, 256, 0, stream>>>(zh, eSrc, rowStart, deg, dinv, b2, xBuf, nullptr, nullptr);
  // layer 3 (fused fcW dot)
  k_gemm_mfma<<<gemmBlocks, 256, 0, stream>>>(xBuf, nullptr, nullptr, Bh3, Bl3, dinv, zh);
  k_agg <<<(N_NODES+3)/4, 256, 0, stream>>>(zh, eSrc, rowStart, deg, dinv, b3, nullptr, fcW, dots);

  k_pool_seg<<<N_GRAPHS, 256, 0, stream>>>(dots, gStart, fcb, out);
}

// Round 5
// 236.353 us; speedup vs baseline: 2.7130x; 1.2072x over previous
//
#include <hip/hip_runtime.h>
#include <hip/hip_fp16.h>

#define N_NODES 50000
#define N_EDGES 800000
#define N_GRAPHS 512
#define C 128
#define NBUCK 196            // ceil(50000/256), bucket = dst>>8
#define A_BLOCKS 200         // 4000 edges each
#define EDGES_PER_A (N_EDGES / A_BLOCKS)
#define SE_CAP 8192          // LDS eSrc staging per bucket (mean 4096, sigma ~64)

typedef __attribute__((ext_vector_type(8))) short short8v;
typedef __attribute__((ext_vector_type(4))) float f32x4;

__device__ __forceinline__ unsigned short f2bf(float f){
  unsigned u = __builtin_bit_cast(unsigned, f);
  unsigned r = u + 0x7FFFu + ((u >> 16) & 1u);
  return (unsigned short)(r >> 16);
}
__device__ __forceinline__ float bf2f(unsigned short h){
  unsigned u = ((unsigned)h) << 16;
  return __builtin_bit_cast(float, u);
}

// ---------- binning pass A1: coarse bucket counts ----------
__global__ __launch_bounds__(256) void k_binCount(const int* __restrict__ dst, int* __restrict__ bucketCount){
  __shared__ int h[256];
  int t = threadIdx.x;
  h[t] = 0; __syncthreads();
  int base = blockIdx.x * EDGES_PER_A;
  for (int i = t; i < EDGES_PER_A; i += 256)
    atomicAdd(&h[dst[base+i] >> 8], 1);
  __syncthreads();
  if (t < NBUCK && h[t] > 0) atomicAdd(&bucketCount[t], h[t]);
}

// ---------- scan bucket counts -> bucketBase (exclusive, 197 entries) + gCursor ----------
__global__ void k_binScan(const int* __restrict__ bucketCount, int* __restrict__ bucketBase,
                          int* __restrict__ gCursor){
  __shared__ int s[256];
  int t = threadIdx.x;
  int v = (t < NBUCK) ? bucketCount[t] : 0;
  s[t] = v; __syncthreads();
  for (int off=1; off<256; off<<=1){
    int u = (t>=off) ? s[t-off] : 0;
    __syncthreads();
    s[t] += u;
    __syncthreads();
  }
  if (t < NBUCK){
    bucketBase[t+1] = s[t];        // inclusive
    gCursor[t] = s[t] - v;         // exclusive
  }
  if (t == 0) bucketBase[0] = 0;
}

// ---------- binning pass A2: scatter packed edges into per-block bucket chunks ----------
__global__ __launch_bounds__(256) void k_binScatter(const int* __restrict__ src, const int* __restrict__ dst,
                           int* __restrict__ gCursor, unsigned* __restrict__ binned){
  __shared__ int h[256], ofs[256], cur[256];
  int t = threadIdx.x;
  h[t] = 0; cur[t] = 0; __syncthreads();
  int base = blockIdx.x * EDGES_PER_A;
  for (int i = t; i < EDGES_PER_A; i += 256)
    atomicAdd(&h[dst[base+i] >> 8], 1);
  __syncthreads();
  if (t < NBUCK && h[t] > 0) ofs[t] = atomicAdd(&gCursor[t], h[t]);
  __syncthreads();
  for (int i = t; i < EDGES_PER_A; i += 256){
    int d = dst[base+i];
    int b = d >> 8;
    int p = atomicAdd(&cur[b], 1);
    binned[ofs[b] + p] = (unsigned)(src[base+i] & 0xFFFF) | ((unsigned)(d & 0xFF) << 16);
  }
}

// ---------- binning pass B: per-bucket CSR finalize (deg/rowStart/dinv/eSrc) ----------
__global__ __launch_bounds__(256) void k_binFinal(const unsigned* __restrict__ binned,
                         const int* __restrict__ bucketBase,
                         unsigned short* __restrict__ eSrc, int* __restrict__ rowStart,
                         int* __restrict__ deg, float* __restrict__ dinv){
  __shared__ int h[256], pre[256], cur[256];
  __shared__ unsigned short sE[SE_CAP];
  int b = blockIdx.x;
  int t = threadIdx.x;
  int base = bucketBase[b], cnt = bucketBase[b+1] - base;
  int nodeBase = b << 8;
  h[t] = 0; __syncthreads();
  for (int i = t; i < cnt; i += 256)
    atomicAdd(&h[binned[base+i] >> 16], 1);
  __syncthreads();
  // inclusive scan of h -> pre
  pre[t] = h[t]; __syncthreads();
  for (int off=1; off<256; off<<=1){
    int u = (t>=off) ? pre[t-off] : 0;
    __syncthreads();
    pre[t] += u;
    __syncthreads();
  }
  int node = nodeBase + t;
  if (node < N_NODES){
    int d = h[t];
    deg[node] = d;
    rowStart[node] = base + pre[t] - d;
    dinv[node] = rsqrtf((float)d + 1.0f);
  }
  cur[t] = pre[t] - h[t];
  __syncthreads();
  for (int i = t; i < cnt; i += 256){
    unsigned v = binned[base+i];
    int dl = v >> 16;
    int p = atomicAdd(&cur[dl], 1);
    unsigned short s = (unsigned short)(v & 0xFFFF);
    if (p < SE_CAP) sE[p] = s;
    else eSrc[base + p] = s;     // overflow fallback (statistically unreachable)
  }
  __syncthreads();
  int lim = cnt < SE_CAP ? cnt : SE_CAP;
  for (int i = t; i < lim; i += 256) eSrc[base+i] = sE[i];
}

// graph segment boundaries from sorted batch (no atomics)
__global__ void k_gstart(const int* __restrict__ batch, int* __restrict__ gStart){
  int i = blockIdx.x*256 + threadIdx.x;
  if (i >= N_NODES) return;
  int b = batch[i];
  int pb = (i==0) ? -1 : batch[i-1];
  for (int g=pb+1; g<=b; g++) gStart[g] = i;
  if (i == N_NODES-1){
    for (int g=b+1; g<=N_GRAPHS; g++) gStart[g] = N_NODES;
  }
}

// ---------- W prepack into MFMA B-fragment layout (hi + lo bf16 split) ----------
__global__ void k_prepack(const float* __restrict__ W, short* __restrict__ Bh, short* __restrict__ Bl){
  int t = blockIdx.x*256 + threadIdx.x;   // 2048 = 32 tiles * 64 lanes
  if (t >= 2048) return;
  int lane = t & 63, tile = t >> 6;       // tile = kt*8 + ct
  int kt = tile >> 3, ct = tile & 7;
  int q = lane >> 4, c = ct*16 + (lane & 15);
  #pragma unroll
  for (int i=0;i<8;i++){
    int k = kt*32 + q*8 + i;
    float w = W[k*C + c];
    unsigned short hh = f2bf(w);
    unsigned short ll = f2bf(w - bf2f(hh));
    Bh[(size_t)(tile*64 + lane)*8 + i] = (short)hh;
    Bl[(size_t)(tile*64 + lane)*8 + i] = (short)ll;
  }
}

// ---------- MFMA GEMM: zh[i][:] = fp16( (x[i] @ W) * dinv[i] ) ----------
// 1 wave = 2 row-tiles (32 rows) x 128 cols; B frags loaded once per (kt,ct)
// feed both tiles (6 MFMA per B-load pair).

__global__ __launch_bounds__(256) void k_gemm_mfma(const float* __restrict__ xin,
            const int* __restrict__ feat, const float* __restrict__ emb,
            const short* __restrict__ Bh, const short* __restrict__ Bl,
            const float* __restrict__ dinv, __half* __restrict__ zh){
  int lane = threadIdx.x & 63;
  int pb = blockIdx.x*4 + (threadIdx.x >> 6);
  int R0 = pb*32;
  if (R0 >= N_NODES) return;
  int r15 = lane & 15, q = lane >> 4;

  int row0 = R0 + r15;        if (row0 >= N_NODES) row0 = N_NODES-1;
  int row1 = R0 + 16 + r15;   if (row1 >= N_NODES) row1 = N_NODES-1;
  const float* xr0 = feat ? (emb + (size_t)feat[row0]*C) : (xin + (size_t)row0*C);
  const float* xr1 = feat ? (emb + (size_t)feat[row1]*C) : (xin + (size_t)row1*C);

  f32x4 acc[2][8];
  #pragma unroll
  for (int T=0;T<2;T++)
    #pragma unroll
    for (int ct=0;ct<8;ct++) acc[T][ct] = (f32x4){0.f,0.f,0.f,0.f};

  const short8v* BH = (const short8v*)Bh;
  const short8v* BL = (const short8v*)Bl;

  #pragma unroll
  for (int kt=0; kt<4; kt++){
    short8v ah0, al0, ah1, al1;
    {
      float4 xa = *(const float4*)(xr0 + kt*32 + q*8);
      float4 xb = *(const float4*)(xr0 + kt*32 + q*8 + 4);
      float xv[8] = {xa.x, xa.y, xa.z, xa.w, xb.x, xb.y, xb.z, xb.w};
      #pragma unroll
      for (int i=0;i<8;i++){
        unsigned short hv = f2bf(xv[i]);
        ah0[i] = (short)hv;
        al0[i] = (short)f2bf(xv[i] - bf2f(hv));
      }
    }
    {
      float4 xa = *(const float4*)(xr1 + kt*32 + q*8);
      float4 xb = *(const float4*)(xr1 + kt*32 + q*8 + 4);
      float xv[8] = {xa.x, xa.y, xa.z, xa.w, xb.x, xb.y, xb.z, xb.w};
      #pragma unroll
      for (int i=0;i<8;i++){
        unsigned short hv = f2bf(xv[i]);
        ah1[i] = (short)hv;
        al1[i] = (short)f2bf(xv[i] - bf2f(hv));
      }
    }
    #pragma unroll
    for (int ct=0; ct<8; ct++){
      short8v bh = BH[(kt*8+ct)*64 + lane];
      short8v bl = BL[(kt*8+ct)*64 + lane];
      acc[0][ct] = __builtin_amdgcn_mfma_f32_16x16x32_bf16(ah0, bh, acc[0][ct], 0, 0, 0);
      acc[0][ct] = __builtin_amdgcn_mfma_f32_16x16x32_bf16(al0, bh, acc[0][ct], 0, 0, 0);
      acc[0][ct] = __builtin_amdgcn_mfma_f32_16x16x32_bf16(ah0, bl, acc[0][ct], 0, 0, 0);
      acc[1][ct] = __builtin_amdgcn_mfma_f32_16x16x32_bf16(ah1, bh, acc[1][ct], 0, 0, 0);
      acc[1][ct] = __builtin_amdgcn_mfma_f32_16x16x32_bf16(al1, bh, acc[1][ct], 0, 0, 0);
      acc[1][ct] = __builtin_amdgcn_mfma_f32_16x16x32_bf16(ah1, bl, acc[1][ct], 0, 0, 0);
    }
  }

  // C/D layout (verified m89): col = ct*16 + (lane&15), row = tileBase + q*4 + j
  #pragma unroll
  for (int T=0;T<2;T++){
    #pragma unroll
    for (int j=0;j<4;j++){
      int rz = R0 + T*16 + q*4 + j;
      if (rz < N_NODES){
        float d = dinv[rz];
        #pragma unroll
        for (int ct=0; ct<8; ct++){
          zh[(size_t)rz*C + ct*16 + r15] = __float2half(acc[T][ct][j] * d);
        }
      }
    }
  }
}

// ---------- aggregation (pure gather via CSR, fp16 operand, fp32 accum) ----------

__global__ __launch_bounds__(256) void k_agg(const __half* __restrict__ zh, const unsigned short* __restrict__ eSrc,
                      const int* __restrict__ rowStart, const int* __restrict__ deg,
                      const float* __restrict__ dinv, const float* __restrict__ b,
                      float* __restrict__ xout, const float* __restrict__ fcW,
                      float* __restrict__ dots){
  int node = blockIdx.x*4 + (threadIdx.x>>6);
  int lane = threadIdx.x & 63;
  if (node >= N_NODES) return;
  int rs = rowStart[node], len = deg[node];
  const __half2* zb = (const __half2*)zh;   // row stride 64 half2
  float2 a = __half22float2(zb[(size_t)node*64 + lane]);
  int k = 0;
  for (; k+4<=len; k+=4){
    int s0 = eSrc[rs+k], s1 = eSrc[rs+k+1], s2 = eSrc[rs+k+2], s3 = eSrc[rs+k+3];
    float2 v0 = __half22float2(zb[(size_t)s0*64 + lane]);
    float2 v1 = __half22float2(zb[(size_t)s1*64 + lane]);
    float2 v2 = __half22float2(zb[(size_t)s2*64 + lane]);
    float2 v3 = __half22float2(zb[(size_t)s3*64 + lane]);
    a.x += v0.x + v1.x + v2.x + v3.x;
    a.y += v0.y + v1.y + v2.y + v3.y;
  }
  for (; k<len; k++){
    float2 v = __half22float2(zb[(size_t)eSrc[rs+k]*64 + lane]);
    a.x += v.x; a.y += v.y;
  }
  float dn = dinv[node];
  float2 bb = ((const float2*)b)[lane];
  float v0 = fmaxf(fmaf(dn, a.x, bb.x), 0.f);
  float v1 = fmaxf(fmaf(dn, a.y, bb.y), 0.f);
  if (dots){
    float2 fw = ((const float2*)fcW)[lane];
    float s = v0*fw.x + v1*fw.y;
    #pragma unroll
    for (int off=32; off>0; off>>=1) s += __shfl_down(s, off);
    if (lane==0) dots[node] = s;
  } else {
    ((float2*)(xout + (size_t)node*C))[lane] = make_float2(v0, v1);
  }
}

// ---------- pooling ----------

__global__ void k_pool_seg(const float* __restrict__ dots, const int* __restrict__ gStart,
                           const float* __restrict__ fcb, float* __restrict__ out){
  __shared__ float s[256];
  int g = blockIdx.x;
  int st = gStart[g], en = gStart[g+1];
  float acc = 0.f;
  for (int i = st + threadIdx.x; i < en; i += 256) acc += dots[i];
  s[threadIdx.x] = acc; __syncthreads();
  for (int off=128; off>0; off>>=1){
    if (threadIdx.x < off) s[threadIdx.x] += s[threadIdx.x+off];
    __syncthreads();
  }
  if (threadIdx.x==0) out[g] = s[0]/fmaxf((float)(en-st),1.0f) + fcb[0];
}

// ---------- launch ----------

extern "C" void kernel_launch(void* const* d_in, const int* in_sizes, int n_in,
                              void* d_out, int out_size, void* d_ws, size_t ws_size,
                              hipStream_t stream){
  const int* edge  = (const int*)d_in[0];
  const int* srcI  = edge;
  const int* dstI  = edge + N_EDGES;
  const int* feat  = (const int*)d_in[1];
  const int* batch = (const int*)d_in[2];
  const float* emb = (const float*)d_in[3];
  const float* W1  = (const float*)d_in[4];
  const float* b1  = (const float*)d_in[5];
  const float* W2  = (const float*)d_in[6];
  const float* b2  = (const float*)d_in[7];
  const float* W3  = (const float*)d_in[8];
  const float* b3  = (const float*)d_in[9];
  const float* fcW = (const float*)d_in[10];
  const float* fcb = (const float*)d_in[11];
  float* out = (float*)d_out;

  float* xBuf = (float*)d_ws;                        // 50000*128 f32
  __half* zh  = (__half*)(xBuf + (size_t)N_NODES*C); // 50000*128 f16
  unsigned* binned = (unsigned*)((char*)zh + (size_t)N_NODES*C*sizeof(__half)); // 800000 u32
  unsigned short* eSrc = (unsigned short*)(binned + N_EDGES);  // 800000 u16
  int* rowStart = (int*)(eSrc + N_EDGES);            // 50000
  int* deg      = rowStart + N_NODES;                // 50000
  float* dinv   = (float*)(deg + N_NODES);           // 50000
  int* bucketCount = (int*)(dinv + N_NODES);         // 256
  int* bucketBase  = bucketCount + 256;              // 257 (+pad)
  int* gCursor     = bucketBase + 260;               // 256
  int* gStart      = gCursor + 256;                  // 513 (+pad)
  float* dots   = (float*)(gStart + 520);            // 50000
  short* Bpack  = (short*)(dots + N_NODES);          // 6 * 16384 shorts
  short* Bh1 = Bpack,           * Bl1 = Bpack + 16384;
  short* Bh2 = Bpack + 2*16384, * Bl2 = Bpack + 3*16384;
  short* Bh3 = Bpack + 4*16384, * Bl3 = Bpack + 5*16384;

  hipMemsetAsync(bucketCount, 0, 256*sizeof(int), stream);

  int nChunks = (N_NODES + 255)/256;  // 196
  k_binCount  <<<A_BLOCKS, 256, 0, stream>>>(dstI, bucketCount);
  k_binScan   <<<1, 256, 0, stream>>>(bucketCount, bucketBase, gCursor);
  k_binScatter<<<A_BLOCKS, 256, 0, stream>>>(srcI, dstI, gCursor, binned);
  k_binFinal  <<<NBUCK, 256, 0, stream>>>(binned, bucketBase, eSrc, rowStart, deg, dinv);
  k_gstart    <<<nChunks, 256, 0, stream>>>(batch, gStart);

  k_prepack<<<8, 256, 0, stream>>>(W1, Bh1, Bl1);
  k_prepack<<<8, 256, 0, stream>>>(W2, Bh2, Bl2);
  k_prepack<<<8, 256, 0, stream>>>(W3, Bh3, Bl3);

  int gemmBlocks = (N_NODES + 127)/128;   // 391: 2 row-tiles per wave, 4 waves/block
  // layer 1 (embedding gather fused)
  k_gemm_mfma<<<gemmBlocks, 256, 0, stream>>>(nullptr, feat, emb, Bh1, Bl1, dinv, zh);
  k_agg <<<(N_NODES+3)/4, 256, 0, stream>>>(zh, eSrc, rowStart, deg, dinv, b1, xBuf, nullptr, nullptr);
  // layer 2
  k_gemm_mfma<<<gemmBlocks, 256, 0, stream>>>(xBuf, nullptr, nullptr, Bh2, Bl2, dinv, zh);
  k_agg <<<(N_NODES+3)/4, 256, 0, stream>>>(zh, eSrc, rowStart, deg, dinv, b2, xBuf, nullptr, nullptr);
  // layer 3 (fused fcW dot)
  k_gemm_mfma<<<gemmBlocks, 256, 0, stream>>>(xBuf, nullptr, nullptr, Bh3, Bl3, dinv, zh);
  k_agg <<<(N_NODES+3)/4, 256, 0, stream>>>(zh, eSrc, rowStart, deg, dinv, b3, nullptr, fcW, dots);

  k_pool_seg<<<N_GRAPHS, 256, 0, stream>>>(dots, gStart, fcb, out);
}

// Round 6
// 228.013 us; speedup vs baseline: 2.8123x; 1.0366x over previous
//
#include <hip/hip_runtime.h>
#include <hip/hip_fp16.h>

#define N_NODES 50000
#define N_EDGES 800000
#define N_GRAPHS 512
#define C 128
#define NBUCK 196            // ceil(50000/256), bucket = dst>>8
#define A_BLOCKS 200         // 4000 edges each
#define EDGES_PER_A (N_EDGES / A_BLOCKS)
#define SE_CAP 8192          // LDS eSrc staging per bucket (mean 4096)

typedef __attribute__((ext_vector_type(8))) short short8v;
typedef __attribute__((ext_vector_type(4))) float f32x4;

__device__ __forceinline__ unsigned short f2bf(float f){
  unsigned u = __builtin_bit_cast(unsigned, f);
  unsigned r = u + 0x7FFFu + ((u >> 16) & 1u);
  return (unsigned short)(r >> 16);
}
__device__ __forceinline__ float bf2f(unsigned short h){
  unsigned u = ((unsigned)h) << 16;
  return __builtin_bit_cast(float, u);
}

// ---------- binning A1: per-block bucket histograms (no global init needed) ----------
__global__ __launch_bounds__(256) void k_binCount(const int* __restrict__ dst, int* __restrict__ blockHist){
  __shared__ int h[256];
  int t = threadIdx.x;
  h[t] = 0; __syncthreads();
  int base = blockIdx.x * EDGES_PER_A;
  for (int i = t; i < EDGES_PER_A; i += 256)
    atomicAdd(&h[dst[base+i] >> 8], 1);
  __syncthreads();
  blockHist[blockIdx.x*256 + t] = h[t];
}

// ---------- scan: bucketBase (257) + per-block chunk offsets (relative) ----------
__global__ void k_binScan(const int* __restrict__ blockHist, int* __restrict__ blockOfs,
                          int* __restrict__ bucketBase){
  __shared__ int s[256];
  int t = threadIdx.x;
  int run = 0;
  for (int b = 0; b < A_BLOCKS; b++){
    int v = blockHist[b*256 + t];
    blockOfs[b*256 + t] = run;
    run += v;
  }
  s[t] = run; __syncthreads();
  for (int off=1; off<256; off<<=1){
    int u = (t>=off) ? s[t-off] : 0;
    __syncthreads();
    s[t] += u;
    __syncthreads();
  }
  bucketBase[t+1] = s[t];
  if (t == 0) bucketBase[0] = 0;
}

// ---------- binning A2: scatter packed edges (no global atomics) ----------
__global__ __launch_bounds__(256) void k_binScatter(const int* __restrict__ src, const int* __restrict__ dst,
                           const int* __restrict__ bucketBase, const int* __restrict__ blockOfs,
                           unsigned* __restrict__ binned){
  __shared__ int ofs[256], cur[256];
  int t = threadIdx.x;
  ofs[t] = bucketBase[t] + blockOfs[blockIdx.x*256 + t];
  cur[t] = 0;
  __syncthreads();
  int base = blockIdx.x * EDGES_PER_A;
  for (int i = t; i < EDGES_PER_A; i += 256){
    int d = dst[base+i];
    int b = d >> 8;
    int p = atomicAdd(&cur[b], 1);
    binned[ofs[b] + p] = (unsigned)(src[base+i] & 0xFFFF) | ((unsigned)(d & 0xFF) << 16);
  }
}

// ---------- binning B: per-bucket CSR finalize (deg/rowStart/dinv/eSrc) ----------
__global__ __launch_bounds__(256) void k_binFinal(const unsigned* __restrict__ binned,
                         const int* __restrict__ bucketBase,
                         unsigned short* __restrict__ eSrc, int* __restrict__ rowStart,
                         int* __restrict__ deg, float* __restrict__ dinv){
  __shared__ int h[256], pre[256], cur[256];
  __shared__ unsigned short sE[SE_CAP];
  int b = blockIdx.x;
  int t = threadIdx.x;
  int base = bucketBase[b], cnt = bucketBase[b+1] - base;
  int nodeBase = b << 8;
  h[t] = 0; __syncthreads();
  for (int i = t; i < cnt; i += 256)
    atomicAdd(&h[binned[base+i] >> 16], 1);
  __syncthreads();
  pre[t] = h[t]; __syncthreads();
  for (int off=1; off<256; off<<=1){
    int u = (t>=off) ? pre[t-off] : 0;
    __syncthreads();
    pre[t] += u;
    __syncthreads();
  }
  int node = nodeBase + t;
  if (node < N_NODES){
    int d = h[t];
    deg[node] = d;
    rowStart[node] = base + pre[t] - d;
    dinv[node] = rsqrtf((float)d + 1.0f);
  }
  cur[t] = pre[t] - h[t];
  __syncthreads();
  for (int i = t; i < cnt; i += 256){
    unsigned v = binned[base+i];
    int dl = v >> 16;
    int p = atomicAdd(&cur[dl], 1);
    unsigned short s = (unsigned short)(v & 0xFFFF);
    if (p < SE_CAP) sE[p] = s;
    else eSrc[base + p] = s;     // overflow fallback
  }
  __syncthreads();
  int lim = cnt < SE_CAP ? cnt : SE_CAP;
  for (int i = t; i < lim; i += 256) eSrc[base+i] = sE[i];
}

// graph segment boundaries from sorted batch
__global__ void k_gstart(const int* __restrict__ batch, int* __restrict__ gStart){
  int i = blockIdx.x*256 + threadIdx.x;
  if (i >= N_NODES) return;
  int b = batch[i];
  int pb = (i==0) ? -1 : batch[i-1];
  for (int g=pb+1; g<=b; g++) gStart[g] = i;
  if (i == N_NODES-1){
    for (int g=b+1; g<=N_GRAPHS; g++) gStart[g] = N_NODES;
  }
}

// ---------- W prepack (all 3 layers, one launch) into MFMA B-frag layout ----------
__global__ void k_prepack3(const float* __restrict__ W1, const float* __restrict__ W2,
                           const float* __restrict__ W3, short* __restrict__ Bp){
  int layer = blockIdx.x >> 3;            // 24 blocks: 8 per layer
  const float* W = (layer==0) ? W1 : (layer==1) ? W2 : W3;
  short* Bh = Bp + (size_t)layer*2*16384;
  short* Bl = Bh + 16384;
  int t = (blockIdx.x & 7)*256 + threadIdx.x;   // 0..2047
  int lane = t & 63, tile = t >> 6;       // tile = kt*8 + ct
  int kt = tile >> 3, ct = tile & 7;
  int q = lane >> 4, c = ct*16 + (lane & 15);
  #pragma unroll
  for (int i=0;i<8;i++){
    int k = kt*32 + q*8 + i;
    float w = W[k*C + c];
    unsigned short hh = f2bf(w);
    unsigned short ll = f2bf(w - bf2f(hh));
    Bh[(size_t)(tile*64 + lane)*8 + i] = (short)hh;
    Bl[(size_t)(tile*64 + lane)*8 + i] = (short)ll;
  }
}

// ---------- MFMA GEMM (layer 1): zh = fp16( (emb[feat] @ W) * dinv ) ----------
// 1 wave = 2 row-tiles (32 rows) x 128 cols; split-bf16: xh*Wh + xl*Wh + xh*Wl.

__global__ __launch_bounds__(256) void k_gemm_mfma_emb(
            const int* __restrict__ feat, const float* __restrict__ emb,
            const short* __restrict__ Bh, const short* __restrict__ Bl,
            const float* __restrict__ dinv, __half* __restrict__ zh){
  int lane = threadIdx.x & 63;
  int pb = blockIdx.x*4 + (threadIdx.x >> 6);
  int R0 = pb*32;
  if (R0 >= N_NODES) return;
  int r15 = lane & 15, q = lane >> 4;
  int row0 = R0 + r15;        if (row0 >= N_NODES) row0 = N_NODES-1;
  int row1 = R0 + 16 + r15;   if (row1 >= N_NODES) row1 = N_NODES-1;
  const float* xr0 = emb + (size_t)feat[row0]*C;
  const float* xr1 = emb + (size_t)feat[row1]*C;

  f32x4 acc[2][8];
  #pragma unroll
  for (int T=0;T<2;T++)
    #pragma unroll
    for (int ct=0;ct<8;ct++) acc[T][ct] = (f32x4){0.f,0.f,0.f,0.f};

  const short8v* BH = (const short8v*)Bh;
  const short8v* BL = (const short8v*)Bl;

  #pragma unroll
  for (int kt=0; kt<4; kt++){
    short8v ah0, al0, ah1, al1;
    {
      float4 xa = *(const float4*)(xr0 + kt*32 + q*8);
      float4 xb = *(const float4*)(xr0 + kt*32 + q*8 + 4);
      float xv[8] = {xa.x, xa.y, xa.z, xa.w, xb.x, xb.y, xb.z, xb.w};
      #pragma unroll
      for (int i=0;i<8;i++){
        unsigned short hv = f2bf(xv[i]);
        ah0[i] = (short)hv;
        al0[i] = (short)f2bf(xv[i] - bf2f(hv));
      }
    }
    {
      float4 xa = *(const float4*)(xr1 + kt*32 + q*8);
      float4 xb = *(const float4*)(xr1 + kt*32 + q*8 + 4);
      float xv[8] = {xa.x, xa.y, xa.z, xa.w, xb.x, xb.y, xb.z, xb.w};
      #pragma unroll
      for (int i=0;i<8;i++){
        unsigned short hv = f2bf(xv[i]);
        ah1[i] = (short)hv;
        al1[i] = (short)f2bf(xv[i] - bf2f(hv));
      }
    }
    #pragma unroll
    for (int ct=0; ct<8; ct++){
      short8v bh = BH[(kt*8+ct)*64 + lane];
      short8v bl = BL[(kt*8+ct)*64 + lane];
      acc[0][ct] = __builtin_amdgcn_mfma_f32_16x16x32_bf16(ah0, bh, acc[0][ct], 0, 0, 0);
      acc[0][ct] = __builtin_amdgcn_mfma_f32_16x16x32_bf16(al0, bh, acc[0][ct], 0, 0, 0);
      acc[0][ct] = __builtin_amdgcn_mfma_f32_16x16x32_bf16(ah0, bl, acc[0][ct], 0, 0, 0);
      acc[1][ct] = __builtin_amdgcn_mfma_f32_16x16x32_bf16(ah1, bh, acc[1][ct], 0, 0, 0);
      acc[1][ct] = __builtin_amdgcn_mfma_f32_16x16x32_bf16(al1, bh, acc[1][ct], 0, 0, 0);
      acc[1][ct] = __builtin_amdgcn_mfma_f32_16x16x32_bf16(ah1, bl, acc[1][ct], 0, 0, 0);
    }
  }
  #pragma unroll
  for (int T=0;T<2;T++){
    #pragma unroll
    for (int j=0;j<4;j++){
      int rz = R0 + T*16 + q*4 + j;
      if (rz < N_NODES){
        float d = dinv[rz];
        #pragma unroll
        for (int ct=0; ct<8; ct++)
          zh[(size_t)rz*C + ct*16 + r15] = __float2half(acc[T][ct][j] * d);
      }
    }
  }
}

// ---------- MFMA GEMM (layers 2-3): zh = fp16( (x_h @ W) * dinv ), x_h fp16 ----------
// fp16 x splits EXACTLY into bf16 hi+lo (11 mantissa bits <= 16).

__global__ __launch_bounds__(256) void k_gemm_mfma_h(
            const __half* __restrict__ xin,
            const short* __restrict__ Bh, const short* __restrict__ Bl,
            const float* __restrict__ dinv, __half* __restrict__ zh){
  int lane = threadIdx.x & 63;
  int pb = blockIdx.x*4 + (threadIdx.x >> 6);
  int R0 = pb*32;
  if (R0 >= N_NODES) return;
  int r15 = lane & 15, q = lane >> 4;
  int row0 = R0 + r15;        if (row0 >= N_NODES) row0 = N_NODES-1;
  int row1 = R0 + 16 + r15;   if (row1 >= N_NODES) row1 = N_NODES-1;
  const __half* xr0 = xin + (size_t)row0*C;
  const __half* xr1 = xin + (size_t)row1*C;

  f32x4 acc[2][8];
  #pragma unroll
  for (int T=0;T<2;T++)
    #pragma unroll
    for (int ct=0;ct<8;ct++) acc[T][ct] = (f32x4){0.f,0.f,0.f,0.f};

  const short8v* BH = (const short8v*)Bh;
  const short8v* BL = (const short8v*)Bl;

  #pragma unroll
  for (int kt=0; kt<4; kt++){
    short8v ah0, al0, ah1, al1;
    {
      short8v hv = *(const short8v*)(xr0 + kt*32 + q*8);
      #pragma unroll
      for (int i=0;i<8;i++){
        float f = __half2float(__builtin_bit_cast(__half, (unsigned short)hv[i]));
        unsigned short hb = f2bf(f);
        ah0[i] = (short)hb;
        al0[i] = (short)f2bf(f - bf2f(hb));
      }
    }
    {
      short8v hv = *(const short8v*)(xr1 + kt*32 + q*8);
      #pragma unroll
      for (int i=0;i<8;i++){
        float f = __half2float(__builtin_bit_cast(__half, (unsigned short)hv[i]));
        unsigned short hb = f2bf(f);
        ah1[i] = (short)hb;
        al1[i] = (short)f2bf(f - bf2f(hb));
      }
    }
    #pragma unroll
    for (int ct=0; ct<8; ct++){
      short8v bh = BH[(kt*8+ct)*64 + lane];
      short8v bl = BL[(kt*8+ct)*64 + lane];
      acc[0][ct] = __builtin_amdgcn_mfma_f32_16x16x32_bf16(ah0, bh, acc[0][ct], 0, 0, 0);
      acc[0][ct] = __builtin_amdgcn_mfma_f32_16x16x32_bf16(al0, bh, acc[0][ct], 0, 0, 0);
      acc[0][ct] = __builtin_amdgcn_mfma_f32_16x16x32_bf16(ah0, bl, acc[0][ct], 0, 0, 0);
      acc[1][ct] = __builtin_amdgcn_mfma_f32_16x16x32_bf16(ah1, bh, acc[1][ct], 0, 0, 0);
      acc[1][ct] = __builtin_amdgcn_mfma_f32_16x16x32_bf16(al1, bh, acc[1][ct], 0, 0, 0);
      acc[1][ct] = __builtin_amdgcn_mfma_f32_16x16x32_bf16(ah1, bl, acc[1][ct], 0, 0, 0);
    }
  }
  #pragma unroll
  for (int T=0;T<2;T++){
    #pragma unroll
    for (int j=0;j<4;j++){
      int rz = R0 + T*16 + q*4 + j;
      if (rz < N_NODES){
        float d = dinv[rz];
        #pragma unroll
        for (int ct=0; ct<8; ct++)
          zh[(size_t)rz*C + ct*16 + r15] = __float2half(acc[T][ct][j] * d);
      }
    }
  }
}

// ---------- aggregation (gather via CSR, fp16 operand, fp32 accum) ----------
// layers 1-2: xout(fp16) = relu(dinv*(z+sum z[src]) + b); layer 3: dot with fcW.

__global__ __launch_bounds__(256) void k_agg(const __half* __restrict__ zh, const unsigned short* __restrict__ eSrc,
                      const int* __restrict__ rowStart, const int* __restrict__ deg,
                      const float* __restrict__ dinv, const float* __restrict__ b,
                      __half* __restrict__ xout, const float* __restrict__ fcW,
                      float* __restrict__ dots){
  int node = blockIdx.x*4 + (threadIdx.x>>6);
  int lane = threadIdx.x & 63;
  if (node >= N_NODES) return;
  int rs = rowStart[node], len = deg[node];
  const __half2* zb = (const __half2*)zh;   // row stride 64 half2
  float2 a = __half22float2(zb[(size_t)node*64 + lane]);
  int k = 0;
  for (; k+4<=len; k+=4){
    int s0 = eSrc[rs+k], s1 = eSrc[rs+k+1], s2 = eSrc[rs+k+2], s3 = eSrc[rs+k+3];
    float2 v0 = __half22float2(zb[(size_t)s0*64 + lane]);
    float2 v1 = __half22float2(zb[(size_t)s1*64 + lane]);
    float2 v2 = __half22float2(zb[(size_t)s2*64 + lane]);
    float2 v3 = __half22float2(zb[(size_t)s3*64 + lane]);
    a.x += v0.x + v1.x + v2.x + v3.x;
    a.y += v0.y + v1.y + v2.y + v3.y;
  }
  for (; k<len; k++){
    float2 v = __half22float2(zb[(size_t)eSrc[rs+k]*64 + lane]);
    a.x += v.x; a.y += v.y;
  }
  float dn = dinv[node];
  float2 bb = ((const float2*)b)[lane];
  float v0 = fmaxf(fmaf(dn, a.x, bb.x), 0.f);
  float v1 = fmaxf(fmaf(dn, a.y, bb.y), 0.f);
  if (dots){
    float2 fw = ((const float2*)fcW)[lane];
    float s = v0*fw.x + v1*fw.y;
    #pragma unroll
    for (int off=32; off>0; off>>=1) s += __shfl_down(s, off);
    if (lane==0) dots[node] = s;
  } else {
    ((__half2*)xout)[(size_t)node*64 + lane] = __float22half2_rn(make_float2(v0, v1));
  }
}

// ---------- pooling ----------

__global__ void k_pool_seg(const float* __restrict__ dots, const int* __restrict__ gStart,
                           const float* __restrict__ fcb, float* __restrict__ out){
  __shared__ float s[256];
  int g = blockIdx.x;
  int st = gStart[g], en = gStart[g+1];
  float acc = 0.f;
  for (int i = st + threadIdx.x; i < en; i += 256) acc += dots[i];
  s[threadIdx.x] = acc; __syncthreads();
  for (int off=128; off>0; off>>=1){
    if (threadIdx.x < off) s[threadIdx.x] += s[threadIdx.x+off];
    __syncthreads();
  }
  if (threadIdx.x==0) out[g] = s[0]/fmaxf((float)(en-st),1.0f) + fcb[0];
}

// ---------- launch ----------

extern "C" void kernel_launch(void* const* d_in, const int* in_sizes, int n_in,
                              void* d_out, int out_size, void* d_ws, size_t ws_size,
                              hipStream_t stream){
  const int* edge  = (const int*)d_in[0];
  const int* srcI  = edge;
  const int* dstI  = edge + N_EDGES;
  const int* feat  = (const int*)d_in[1];
  const int* batch = (const int*)d_in[2];
  const float* emb = (const float*)d_in[3];
  const float* W1  = (const float*)d_in[4];
  const float* b1  = (const float*)d_in[5];
  const float* W2  = (const float*)d_in[6];
  const float* b2  = (const float*)d_in[7];
  const float* W3  = (const float*)d_in[8];
  const float* b3  = (const float*)d_in[9];
  const float* fcW = (const float*)d_in[10];
  const float* fcb = (const float*)d_in[11];
  float* out = (float*)d_out;

  __half* xh  = (__half*)d_ws;                       // 50000*128 f16
  __half* zh  = xh + (size_t)N_NODES*C;              // 50000*128 f16
  unsigned* binned = (unsigned*)(zh + (size_t)N_NODES*C); // 800000 u32
  unsigned short* eSrc = (unsigned short*)(binned + N_EDGES);  // 800000 u16
  int* rowStart = (int*)(eSrc + N_EDGES);            // 50000
  int* deg      = rowStart + N_NODES;                // 50000
  float* dinv   = (float*)(deg + N_NODES);           // 50000
  int* blockHist = (int*)(dinv + N_NODES);           // 200*256
  int* blockOfs  = blockHist + A_BLOCKS*256;         // 200*256
  int* bucketBase = blockOfs + A_BLOCKS*256;         // 257 (+pad)
  int* gStart     = bucketBase + 260;                // 513 (+pad)
  float* dots   = (float*)(gStart + 520);            // 50000
  short* Bpack  = (short*)(dots + N_NODES);          // 6*16384 shorts
  short* Bh1 = Bpack,           * Bl1 = Bpack + 16384;
  short* Bh2 = Bpack + 2*16384, * Bl2 = Bpack + 3*16384;
  short* Bh3 = Bpack + 4*16384, * Bl3 = Bpack + 5*16384;

  int nChunks = (N_NODES + 255)/256;  // 196
  k_binCount  <<<A_BLOCKS, 256, 0, stream>>>(dstI, blockHist);
  k_binScan   <<<1, 256, 0, stream>>>(blockHist, blockOfs, bucketBase);
  k_binScatter<<<A_BLOCKS, 256, 0, stream>>>(srcI, dstI, bucketBase, blockOfs, binned);
  k_binFinal  <<<NBUCK, 256, 0, stream>>>(binned, bucketBase, eSrc, rowStart, deg, dinv);
  k_gstart    <<<nChunks, 256, 0, stream>>>(batch, gStart);
  k_prepack3  <<<24, 256, 0, stream>>>(W1, W2, W3, Bpack);

  int gemmBlocks = (N_NODES + 127)/128;   // 391
  // layer 1 (embedding gather fused)
  k_gemm_mfma_emb<<<gemmBlocks, 256, 0, stream>>>(feat, emb, Bh1, Bl1, dinv, zh);
  k_agg <<<(N_NODES+3)/4, 256, 0, stream>>>(zh, eSrc, rowStart, deg, dinv, b1, xh, nullptr, nullptr);
  // layer 2
  k_gemm_mfma_h<<<gemmBlocks, 256, 0, stream>>>(xh, Bh2, Bl2, dinv, zh);
  k_agg <<<(N_NODES+3)/4, 256, 0, stream>>>(zh, eSrc, rowStart, deg, dinv, b2, xh, nullptr, nullptr);
  // layer 3 (fused fcW dot)
  k_gemm_mfma_h<<<gemmBlocks, 256, 0, stream>>>(xh, Bh3, Bl3, dinv, zh);
  k_agg <<<(N_NODES+3)/4, 256, 0, stream>>>(zh, eSrc, rowStart, deg, dinv, b3, nullptr, fcW, dots);

  k_pool_seg<<<N_GRAPHS, 256, 0, stream>>>(dots, gStart, fcb, out);
}

// Round 7
// 224.304 us; speedup vs baseline: 2.8588x; 1.0165x over previous
//
#include <hip/hip_runtime.h>
#include <hip/hip_fp16.h>

#define N_NODES 50000
#define N_EDGES 800000
#define N_GRAPHS 512
#define VOCAB 10000
#define C 128
#define NBUCK 196            // ceil(50000/256), bucket = dst>>8
#define A_BLOCKS 200         // 4000 edges each
#define EDGES_PER_A (N_EDGES / A_BLOCKS)
#define SE_CAP 8192          // LDS eSrc staging per bucket (mean 4096)

typedef __attribute__((ext_vector_type(8))) short short8v;
typedef __attribute__((ext_vector_type(4))) float f32x4;

__device__ __forceinline__ unsigned short f2bf(float f){
  unsigned u = __builtin_bit_cast(unsigned, f);
  unsigned r = u + 0x7FFFu + ((u >> 16) & 1u);
  return (unsigned short)(r >> 16);
}
__device__ __forceinline__ float bf2f(unsigned short h){
  unsigned u = ((unsigned)h) << 16;
  return __builtin_bit_cast(float, u);
}

// ---------- binning A1: per-block bucket histograms ----------
__global__ __launch_bounds__(256) void k_binCount(const int* __restrict__ dst, int* __restrict__ blockHist){
  __shared__ int h[256];
  int t = threadIdx.x;
  h[t] = 0; __syncthreads();
  int base = blockIdx.x * EDGES_PER_A;
  for (int i = t; i < EDGES_PER_A; i += 256)
    atomicAdd(&h[dst[base+i] >> 8], 1);
  __syncthreads();
  blockHist[blockIdx.x*256 + t] = h[t];
}

// ---------- scan: bucketBase + per-block chunk offsets ----------
__global__ void k_binScan(const int* __restrict__ blockHist, int* __restrict__ blockOfs,
                          int* __restrict__ bucketBase){
  __shared__ int s[256];
  int t = threadIdx.x;
  int run = 0;
  for (int b = 0; b < A_BLOCKS; b++){
    int v = blockHist[b*256 + t];
    blockOfs[b*256 + t] = run;
    run += v;
  }
  s[t] = run; __syncthreads();
  for (int off=1; off<256; off<<=1){
    int u = (t>=off) ? s[t-off] : 0;
    __syncthreads();
    s[t] += u;
    __syncthreads();
  }
  bucketBase[t+1] = s[t];
  if (t == 0) bucketBase[0] = 0;
}

// ---------- binning A2: scatter packed edges (no global atomics) ----------
__global__ __launch_bounds__(256) void k_binScatter(const int* __restrict__ src, const int* __restrict__ dst,
                           const int* __restrict__ bucketBase, const int* __restrict__ blockOfs,
                           unsigned* __restrict__ binned){
  __shared__ int ofs[256], cur[256];
  int t = threadIdx.x;
  ofs[t] = bucketBase[t] + blockOfs[blockIdx.x*256 + t];
  cur[t] = 0;
  __syncthreads();
  int base = blockIdx.x * EDGES_PER_A;
  for (int i = t; i < EDGES_PER_A; i += 256){
    int d = dst[base+i];
    int b = d >> 8;
    int p = atomicAdd(&cur[b], 1);
    binned[ofs[b] + p] = (unsigned)(src[base+i] & 0xFFFF) | ((unsigned)(d & 0xFF) << 16);
  }
}

// ---------- binning B: per-bucket CSR finalize ----------
__global__ __launch_bounds__(256) void k_binFinal(const unsigned* __restrict__ binned,
                         const int* __restrict__ bucketBase,
                         unsigned short* __restrict__ eSrc, int* __restrict__ rowStart,
                         int* __restrict__ deg, float* __restrict__ dinv){
  __shared__ int h[256], pre[256], cur[256];
  __shared__ unsigned short sE[SE_CAP];
  int b = blockIdx.x;
  int t = threadIdx.x;
  int base = bucketBase[b], cnt = bucketBase[b+1] - base;
  int nodeBase = b << 8;
  h[t] = 0; __syncthreads();
  for (int i = t; i < cnt; i += 256)
    atomicAdd(&h[binned[base+i] >> 16], 1);
  __syncthreads();
  pre[t] = h[t]; __syncthreads();
  for (int off=1; off<256; off<<=1){
    int u = (t>=off) ? pre[t-off] : 0;
    __syncthreads();
    pre[t] += u;
    __syncthreads();
  }
  int node = nodeBase + t;
  if (node < N_NODES){
    int d = h[t];
    deg[node] = d;
    rowStart[node] = base + pre[t] - d;
    dinv[node] = rsqrtf((float)d + 1.0f);
  }
  cur[t] = pre[t] - h[t];
  __syncthreads();
  for (int i = t; i < cnt; i += 256){
    unsigned v = binned[base+i];
    int dl = v >> 16;
    int p = atomicAdd(&cur[dl], 1);
    unsigned short s = (unsigned short)(v & 0xFFFF);
    if (p < SE_CAP) sE[p] = s;
    else eSrc[base + p] = s;
  }
  __syncthreads();
  int lim = cnt < SE_CAP ? cnt : SE_CAP;
  for (int i = t; i < lim; i += 256) eSrc[base+i] = sE[i];
}

// ---------- prep: gstart | W-prepack | emb->fp16 | per-edge (feat,dinv) ----------
__global__ __launch_bounds__(256) void k_prep(const int* __restrict__ batch, int* __restrict__ gStart,
                       const float* __restrict__ W1, const float* __restrict__ W2,
                       const float* __restrict__ W3, short* __restrict__ Bp,
                       const float* __restrict__ emb, __half* __restrict__ embh,
                       const unsigned short* __restrict__ eSrc, const int* __restrict__ feat,
                       const float* __restrict__ dinv,
                       unsigned short* __restrict__ eFeat, float* __restrict__ eDinv){
  int b = blockIdx.x, t = threadIdx.x;
  if (b < NBUCK){                       // gstart
    int i = b*256 + t;
    if (i >= N_NODES) return;
    int bb = batch[i];
    int pb = (i==0) ? -1 : batch[i-1];
    for (int g=pb+1; g<=bb; g++) gStart[g] = i;
    if (i == N_NODES-1)
      for (int g=bb+1; g<=N_GRAPHS; g++) gStart[g] = N_NODES;
  } else if (b < NBUCK+24){             // W prepack (3 layers x 2048 threads)
    int idx = (b-NBUCK)*256 + t;        // 0..6143
    int layer = idx / 2048;
    int r = idx - layer*2048;
    const float* W = (layer==0) ? W1 : (layer==1) ? W2 : W3;
    short* Bh = Bp + (size_t)layer*32768;
    short* Bl = Bh + 16384;
    int lane = r & 63, tile = r >> 6;   // tile = kt*8 + ct
    int kt = tile >> 3, ct = tile & 7;
    int q = lane >> 4, c = ct*16 + (lane & 15);
    #pragma unroll
    for (int i=0;i<8;i++){
      int k = kt*32 + q*8 + i;
      float w = W[k*C + c];
      unsigned short hh = f2bf(w);
      unsigned short ll = f2bf(w - bf2f(hh));
      Bh[(size_t)(tile*64 + lane)*8 + i] = (short)hh;
      Bl[(size_t)(tile*64 + lane)*8 + i] = (short)ll;
    }
  } else if (b < NBUCK+24+64){          // emb -> fp16
    int idx = (b-NBUCK-24)*256 + t;
    const float2* s = (const float2*)emb;
    __half2* d2 = (__half2*)embh;
    for (int i = idx; i < VOCAB*C/2; i += 64*256)
      d2[i] = __float22half2_rn(s[i]);
  } else {                              // per-edge metadata (200 blocks)
    int idx = (b-NBUCK-24-64)*256 + t;
    for (int e = idx; e < N_EDGES; e += 200*256){
      int s = eSrc[e];
      eFeat[e] = (unsigned short)feat[s];
      eDinv[e] = dinv[s];
    }
  }
}

// ---------- agg layer 1 (embedding space; working set = embh 2.56MB, L2-resident) ----------
// u[i] = fp16( dinv_i * ( dinv_i*embh[feat_i] + sum_e eDinv[e]*embh[eFeat[e]] ) )

__global__ __launch_bounds__(256) void k_agg1(const __half* __restrict__ embh,
                      const unsigned short* __restrict__ eFeat, const float* __restrict__ eDinv,
                      const int* __restrict__ rowStart, const int* __restrict__ deg,
                      const float* __restrict__ dinv, const int* __restrict__ feat,
                      __half* __restrict__ uout){
  int node = blockIdx.x*4 + (threadIdx.x>>6);
  int lane = threadIdx.x & 63;
  if (node >= N_NODES) return;
  int rs = rowStart[node], len = deg[node];
  float dn = dinv[node];
  const __half2* E = (const __half2*)embh;   // row stride 64 half2
  float2 sv = __half22float2(E[(size_t)feat[node]*64 + lane]);
  float2 a = make_float2(dn*sv.x, dn*sv.y);
  int k = 0;
  for (; k+4<=len; k+=4){
    int f0 = eFeat[rs+k], f1 = eFeat[rs+k+1], f2 = eFeat[rs+k+2], f3 = eFeat[rs+k+3];
    float d0 = eDinv[rs+k], d1 = eDinv[rs+k+1], d2 = eDinv[rs+k+2], d3 = eDinv[rs+k+3];
    float2 v0 = __half22float2(E[(size_t)f0*64 + lane]);
    float2 v1 = __half22float2(E[(size_t)f1*64 + lane]);
    float2 v2 = __half22float2(E[(size_t)f2*64 + lane]);
    float2 v3 = __half22float2(E[(size_t)f3*64 + lane]);
    a.x = fmaf(d0, v0.x, a.x); a.y = fmaf(d0, v0.y, a.y);
    a.x = fmaf(d1, v1.x, a.x); a.y = fmaf(d1, v1.y, a.y);
    a.x = fmaf(d2, v2.x, a.x); a.y = fmaf(d2, v2.y, a.y);
    a.x = fmaf(d3, v3.x, a.x); a.y = fmaf(d3, v3.y, a.y);
  }
  for (; k<len; k++){
    float dd = eDinv[rs+k];
    float2 v = __half22float2(E[(size_t)eFeat[rs+k]*64 + lane]);
    a.x = fmaf(dd, v.x, a.x); a.y = fmaf(dd, v.y, a.y);
  }
  ((__half2*)uout)[(size_t)node*64 + lane] = __float22half2_rn(make_float2(dn*a.x, dn*a.y));
}

// ---------- agg layers 2-3 (xs space): u[i] = fp16( dinv_i*(xs_i + sum xs_src) ) ----------

__global__ __launch_bounds__(256) void k_aggS(const __half* __restrict__ xs, const unsigned short* __restrict__ eSrc,
                      const int* __restrict__ rowStart, const int* __restrict__ deg,
                      const float* __restrict__ dinv, __half* __restrict__ uout){
  int node = blockIdx.x*4 + (threadIdx.x>>6);
  int lane = threadIdx.x & 63;
  if (node >= N_NODES) return;
  int rs = rowStart[node], len = deg[node];
  const __half2* zb = (const __half2*)xs;
  float2 a = __half22float2(zb[(size_t)node*64 + lane]);
  int k = 0;
  for (; k+4<=len; k+=4){
    int s0 = eSrc[rs+k], s1 = eSrc[rs+k+1], s2 = eSrc[rs+k+2], s3 = eSrc[rs+k+3];
    float2 v0 = __half22float2(zb[(size_t)s0*64 + lane]);
    float2 v1 = __half22float2(zb[(size_t)s1*64 + lane]);
    float2 v2 = __half22float2(zb[(size_t)s2*64 + lane]);
    float2 v3 = __half22float2(zb[(size_t)s3*64 + lane]);
    a.x += v0.x + v1.x + v2.x + v3.x;
    a.y += v0.y + v1.y + v2.y + v3.y;
  }
  for (; k<len; k++){
    float2 v = __half22float2(zb[(size_t)eSrc[rs+k]*64 + lane]);
    a.x += v.x; a.y += v.y;
  }
  float dn = dinv[node];
  ((__half2*)uout)[(size_t)node*64 + lane] = __float22half2_rn(make_float2(dn*a.x, dn*a.y));
}

// ---------- MFMA body shared by both gemm kernels (A = fp16 u, split-bf16 exact) ----------

#define GEMM_BODY(XR0, XR1) \
  f32x4 acc[2][8]; \
  _Pragma("unroll") for (int T=0;T<2;T++) \
    _Pragma("unroll") for (int ct=0;ct<8;ct++) acc[T][ct] = (f32x4){0.f,0.f,0.f,0.f}; \
  const short8v* BH = (const short8v*)Bh; \
  const short8v* BL = (const short8v*)Bl; \
  _Pragma("unroll") \
  for (int kt=0; kt<4; kt++){ \
    short8v ah0, al0, ah1, al1; \
    { short8v hv = *(const short8v*)(XR0 + kt*32 + q*8); \
      _Pragma("unroll") for (int i=0;i<8;i++){ \
        float f = __half2float(__builtin_bit_cast(__half, (unsigned short)hv[i])); \
        unsigned short hb = f2bf(f); ah0[i] = (short)hb; al0[i] = (short)f2bf(f - bf2f(hb)); } } \
    { short8v hv = *(const short8v*)(XR1 + kt*32 + q*8); \
      _Pragma("unroll") for (int i=0;i<8;i++){ \
        float f = __half2float(__builtin_bit_cast(__half, (unsigned short)hv[i])); \
        unsigned short hb = f2bf(f); ah1[i] = (short)hb; al1[i] = (short)f2bf(f - bf2f(hb)); } } \
    _Pragma("unroll") \
    for (int ct=0; ct<8; ct++){ \
      short8v bh = BH[(kt*8+ct)*64 + lane]; \
      short8v bl = BL[(kt*8+ct)*64 + lane]; \
      acc[0][ct] = __builtin_amdgcn_mfma_f32_16x16x32_bf16(ah0, bh, acc[0][ct], 0, 0, 0); \
      acc[0][ct] = __builtin_amdgcn_mfma_f32_16x16x32_bf16(al0, bh, acc[0][ct], 0, 0, 0); \
      acc[0][ct] = __builtin_amdgcn_mfma_f32_16x16x32_bf16(ah0, bl, acc[0][ct], 0, 0, 0); \
      acc[1][ct] = __builtin_amdgcn_mfma_f32_16x16x32_bf16(ah1, bh, acc[1][ct], 0, 0, 0); \
      acc[1][ct] = __builtin_amdgcn_mfma_f32_16x16x32_bf16(al1, bh, acc[1][ct], 0, 0, 0); \
      acc[1][ct] = __builtin_amdgcn_mfma_f32_16x16x32_bf16(ah1, bl, acc[1][ct], 0, 0, 0); \
    } \
  }

// ---------- gemm layers 1-2: xs = fp16( dinv * relu(u@W + b) ) ----------

__global__ __launch_bounds__(256) void k_gemmA(
            const __half* __restrict__ uin,
            const short* __restrict__ Bh, const short* __restrict__ Bl,
            const float* __restrict__ bias, const float* __restrict__ dinv,
            __half* __restrict__ xs){
  int lane = threadIdx.x & 63;
  int pb = blockIdx.x*4 + (threadIdx.x >> 6);
  int R0 = pb*32;
  if (R0 >= N_NODES) return;
  int r15 = lane & 15, q = lane >> 4;
  int row0 = R0 + r15;        if (row0 >= N_NODES) row0 = N_NODES-1;
  int row1 = R0 + 16 + r15;   if (row1 >= N_NODES) row1 = N_NODES-1;
  const __half* xr0 = uin + (size_t)row0*C;
  const __half* xr1 = uin + (size_t)row1*C;
  GEMM_BODY(xr0, xr1)
  float bb[8];
  #pragma unroll
  for (int ct=0;ct<8;ct++) bb[ct] = bias[ct*16 + r15];
  #pragma unroll
  for (int T=0;T<2;T++){
    #pragma unroll
    for (int j=0;j<4;j++){
      int rz = R0 + T*16 + q*4 + j;
      if (rz < N_NODES){
        float d = dinv[rz];
        #pragma unroll
        for (int ct=0; ct<8; ct++){
          float v = fmaxf(acc[T][ct][j] + bb[ct], 0.f);
          xs[(size_t)rz*C + ct*16 + r15] = __float2half(v * d);
        }
      }
    }
  }
}

// ---------- gemm layer 3: dots[i] = relu(u@W3 + b3) . fcW ----------

__global__ __launch_bounds__(256) void k_gemm3(
            const __half* __restrict__ uin,
            const short* __restrict__ Bh, const short* __restrict__ Bl,
            const float* __restrict__ bias, const float* __restrict__ fcW,
            float* __restrict__ dots){
  int lane = threadIdx.x & 63;
  int pb = blockIdx.x*4 + (threadIdx.x >> 6);
  int R0 = pb*32;
  if (R0 >= N_NODES) return;
  int r15 = lane & 15, q = lane >> 4;
  int row0 = R0 + r15;        if (row0 >= N_NODES) row0 = N_NODES-1;
  int row1 = R0 + 16 + r15;   if (row1 >= N_NODES) row1 = N_NODES-1;
  const __half* xr0 = uin + (size_t)row0*C;
  const __half* xr1 = uin + (size_t)row1*C;
  GEMM_BODY(xr0, xr1)
  float bb[8], fw[8];
  #pragma unroll
  for (int ct=0;ct<8;ct++){ bb[ct] = bias[ct*16 + r15]; fw[ct] = fcW[ct*16 + r15]; }
  #pragma unroll
  for (int T=0;T<2;T++){
    #pragma unroll
    for (int j=0;j<4;j++){
      int rz = R0 + T*16 + q*4 + j;
      float s = 0.f;
      #pragma unroll
      for (int ct=0; ct<8; ct++)
        s += fmaxf(acc[T][ct][j] + bb[ct], 0.f) * fw[ct];
      s += __shfl_xor(s, 1);
      s += __shfl_xor(s, 2);
      s += __shfl_xor(s, 4);
      s += __shfl_xor(s, 8);
      if (r15 == 0 && rz < N_NODES) dots[rz] = s;
    }
  }
}

// ---------- pooling ----------

__global__ void k_pool_seg(const float* __restrict__ dots, const int* __restrict__ gStart,
                           const float* __restrict__ fcb, float* __restrict__ out){
  __shared__ float s[256];
  int g = blockIdx.x;
  int st = gStart[g], en = gStart[g+1];
  float acc = 0.f;
  for (int i = st + threadIdx.x; i < en; i += 256) acc += dots[i];
  s[threadIdx.x] = acc; __syncthreads();
  for (int off=128; off>0; off>>=1){
    if (threadIdx.x < off) s[threadIdx.x] += s[threadIdx.x+off];
    __syncthreads();
  }
  if (threadIdx.x==0) out[g] = s[0]/fmaxf((float)(en-st),1.0f) + fcb[0];
}

// ---------- launch ----------

extern "C" void kernel_launch(void* const* d_in, const int* in_sizes, int n_in,
                              void* d_out, int out_size, void* d_ws, size_t ws_size,
                              hipStream_t stream){
  const int* edge  = (const int*)d_in[0];
  const int* srcI  = edge;
  const int* dstI  = edge + N_EDGES;
  const int* feat  = (const int*)d_in[1];
  const int* batch = (const int*)d_in[2];
  const float* emb = (const float*)d_in[3];
  const float* W1  = (const float*)d_in[4];
  const float* b1  = (const float*)d_in[5];
  const float* W2  = (const float*)d_in[6];
  const float* b2  = (const float*)d_in[7];
  const float* W3  = (const float*)d_in[8];
  const float* b3  = (const float*)d_in[9];
  const float* fcW = (const float*)d_in[10];
  const float* fcb = (const float*)d_in[11];
  float* out = (float*)d_out;

  __half* bufA = (__half*)d_ws;                      // u   50000*128 f16
  __half* bufB = bufA + (size_t)N_NODES*C;           // xs  50000*128 f16
  __half* embh = bufB + (size_t)N_NODES*C;           // 10000*128 f16
  unsigned* binned = (unsigned*)(embh + (size_t)VOCAB*C); // 800000 u32
  unsigned short* eSrc  = (unsigned short*)(binned + N_EDGES);  // 800000 u16
  unsigned short* eFeat = eSrc + N_EDGES;            // 800000 u16
  float* eDinv  = (float*)(eFeat + N_EDGES);         // 800000 f32
  int* rowStart = (int*)(eDinv + N_EDGES);           // 50000
  int* deg      = rowStart + N_NODES;                // 50000
  float* dinv   = (float*)(deg + N_NODES);           // 50000
  int* blockHist = (int*)(dinv + N_NODES);           // 200*256
  int* blockOfs  = blockHist + A_BLOCKS*256;         // 200*256
  int* bucketBase = blockOfs + A_BLOCKS*256;         // 257 (+pad)
  int* gStart     = bucketBase + 260;                // 513 (+pad)
  float* dots   = (float*)(gStart + 520);            // 50000
  short* Bpack  = (short*)(dots + N_NODES);          // 6*16384 shorts
  short* Bh1 = Bpack,           * Bl1 = Bpack + 16384;
  short* Bh2 = Bpack + 2*16384, * Bl2 = Bpack + 3*16384;
  short* Bh3 = Bpack + 4*16384, * Bl3 = Bpack + 5*16384;

  k_binCount  <<<A_BLOCKS, 256, 0, stream>>>(dstI, blockHist);
  k_binScan   <<<1, 256, 0, stream>>>(blockHist, blockOfs, bucketBase);
  k_binScatter<<<A_BLOCKS, 256, 0, stream>>>(srcI, dstI, bucketBase, blockOfs, binned);
  k_binFinal  <<<NBUCK, 256, 0, stream>>>(binned, bucketBase, eSrc, rowStart, deg, dinv);
  k_prep      <<<NBUCK+24+64+200, 256, 0, stream>>>(batch, gStart, W1, W2, W3, Bpack,
                                                    emb, embh, eSrc, feat, dinv, eFeat, eDinv);

  int aggBlocks  = (N_NODES+3)/4;         // 12500
  int gemmBlocks = (N_NODES + 127)/128;   // 391
  // layer 1: aggregate in embedding space (2.56MB working set), then GEMM
  k_agg1 <<<aggBlocks, 256, 0, stream>>>(embh, eFeat, eDinv, rowStart, deg, dinv, feat, bufA);
  k_gemmA<<<gemmBlocks, 256, 0, stream>>>(bufA, Bh1, Bl1, b1, dinv, bufB);
  // layer 2
  k_aggS <<<aggBlocks, 256, 0, stream>>>(bufB, eSrc, rowStart, deg, dinv, bufA);
  k_gemmA<<<gemmBlocks, 256, 0, stream>>>(bufA, Bh2, Bl2, b2, dinv, bufB);
  // layer 3: gemm emits per-node dot with fcW directly
  k_aggS <<<aggBlocks, 256, 0, stream>>>(bufB, eSrc, rowStart, deg, dinv, bufA);
  k_gemm3<<<gemmBlocks, 256, 0, stream>>>(bufA, Bh3, Bl3, b3, fcW, dots);

  k_pool_seg<<<N_GRAPHS, 256, 0, stream>>>(dots, gStart, fcb, out);
}